// Round 14
// baseline (774.779 us; speedup 1.0000x reference)
//
#include <hip/hip_runtime.h>
#include <math.h>

#define TB 2
#define TS 2048
#define TD 1024
#define TH 16
#define TDH 64
#define TF 4096
#define TE 8
#define TT 4096                 // B*S tokens
#define PSTR (TB*TH*TS*TDH)     // 4194304 elements per q/k/v part

typedef __attribute__((ext_vector_type(8))) __bf16 bf16x8;
typedef __attribute__((ext_vector_type(4))) float f32x4;
typedef __attribute__((ext_vector_type(8))) short short8;
typedef __attribute__((ext_vector_type(4))) unsigned short ushort4v;
typedef __attribute__((ext_vector_type(4))) float fvec4;

__device__ inline unsigned short f2bf(float f) {
  union { float f; unsigned int u; } v; v.f = f;
  unsigned int u = v.u;
  unsigned int r = (u + 0x7FFFu + ((u >> 16) & 1u)) >> 16;
  return (unsigned short)r;
}
__device__ inline float bf2f(unsigned short h) {
  union { unsigned int u; float f; } v; v.u = ((unsigned int)h) << 16; return v.f;
}
// 2-way bf16 split: h+m reproduces ~17 mantissa bits (residual ~2^-18)
__device__ inline void split2(float x, unsigned short& h, unsigned short& m) {
  h = f2bf(x);
  m = f2bf(x - bf2f(h));
}

__device__ inline f32x4 mfma_bf16(short8 a, short8 b, f32x4 c) {
  return __builtin_amdgcn_mfma_f32_16x16x32_bf16(
      __builtin_bit_cast(bf16x8, a), __builtin_bit_cast(bf16x8, b), c, 0, 0, 0);
}

// async global->LDS, 16B per lane. LDS dest = wave-uniform base + lane*16.
__device__ inline void gload16(const void* g, void* l) {
  __builtin_amdgcn_global_load_lds(
      (const __attribute__((address_space(1))) void*)g,
      (__attribute__((address_space(3))) void*)l, 16, 0, 0);
}

// fast exact-GELU: erf via Abramowitz-Stegun 7.1.26 (|abs err| < 1.5e-7)
__device__ inline float gelu_f(float v) {
  float ax = fabsf(v) * 0.70710678118654752f;
  float t = __builtin_amdgcn_rcpf(1.0f + 0.3275911f * ax);
  float poly = ((((1.061405429f * t - 1.453152027f) * t + 1.421413741f) * t
                 - 0.284496736f) * t + 0.254829592f) * t;
  float er = 1.0f - poly * __expf(-ax * ax);
  er = copysignf(er, v);
  return 0.5f * v * (1.0f + er);
}

// ---------------- transpose + f32->bf16 convert: in [R,C] f32 -> out [C,R] bf16
__global__ __launch_bounds__(256)
void tcvt_kernel(const float* __restrict__ In, unsigned short* __restrict__ Out,
                 int R, int C) {
  __shared__ float tile[32][33];
  In  += (size_t)blockIdx.z * R * C;
  Out += (size_t)blockIdx.z * R * C;
  int c0 = blockIdx.x * 32, r0 = blockIdx.y * 32;
  int tx = threadIdx.x & 31, ty = threadIdx.x >> 5;  // ty 0..7
#pragma unroll
  for (int i = 0; i < 4; ++i)
    tile[ty + 8*i][tx] = In[(size_t)(r0 + ty + 8*i) * C + c0 + tx];
  __syncthreads();
#pragma unroll
  for (int i = 0; i < 4; ++i)
    Out[(size_t)(c0 + ty + 8*i) * R + r0 + tx] = f2bf(tile[tx][ty + 8*i]);
}

// ---------------- transpose + 2-way split: in [R,C] f32 -> 2x [C,R] bf16
__global__ __launch_bounds__(256)
void tcvt_split_kernel(const float* __restrict__ In,
                       unsigned short* __restrict__ O0,
                       unsigned short* __restrict__ O1, int R, int C) {
  __shared__ float tile[32][33];
  int c0 = blockIdx.x * 32, r0 = blockIdx.y * 32;
  int tx = threadIdx.x & 31, ty = threadIdx.x >> 5;
#pragma unroll
  for (int i = 0; i < 4; ++i)
    tile[ty + 8*i][tx] = In[(size_t)(r0 + ty + 8*i) * C + c0 + tx];
  __syncthreads();
#pragma unroll
  for (int i = 0; i < 4; ++i) {
    float v = tile[tx][ty + 8*i];
    unsigned short h, m; split2(v, h, m);
    size_t idx = (size_t)(c0 + ty + 8*i) * R + r0 + tx;
    O0[idx] = h; O1[idx] = m;
  }
}

// ---------------- RMSNorm f32 in -> bf16 out (for MoE expert input h2)
__global__ __launch_bounds__(256)
void rmsnorm_kernel(const float* __restrict__ X, const float* __restrict__ W,
                    unsigned short* __restrict__ O) {
  int row = blockIdx.x;
  int tid = threadIdx.x;
  int lane = tid & 63, wave = tid >> 6;
  const float* xr = X + (size_t)row * TD;
  fvec4 v = *(const fvec4*)(xr + tid * 4);
  float ss = v[0]*v[0] + v[1]*v[1] + v[2]*v[2] + v[3]*v[3];
#pragma unroll
  for (int msk = 1; msk < 64; msk <<= 1) ss += __shfl_xor(ss, msk);
  __shared__ float red[4];
  if (lane == 0) red[wave] = ss;
  __syncthreads();
  ss = red[0] + red[1] + red[2] + red[3];
  float rs = rsqrtf(ss * (1.0f / TD) + 1e-6f);
  fvec4 wv = *(const fvec4*)(W + tid * 4);
  ushort4v o;
#pragma unroll
  for (int j = 0; j < 4; ++j) o[j] = f2bf(v[j] * rs * wv[j]);
  *(ushort4v*)(O + (size_t)row * TD + tid * 4) = o;
}

// ---------------- RMSNorm f32 in -> pre-split bf16 pair (attention input h1)
__global__ __launch_bounds__(256)
void rmsnorm_split_kernel(const float* __restrict__ X, const float* __restrict__ W,
                          unsigned short* __restrict__ O0,
                          unsigned short* __restrict__ O1) {
  int row = blockIdx.x;
  int tid = threadIdx.x;
  int lane = tid & 63, wave = tid >> 6;
  const float* xr = X + (size_t)row * TD;
  fvec4 v = *(const fvec4*)(xr + tid * 4);
  float ss = v[0]*v[0] + v[1]*v[1] + v[2]*v[2] + v[3]*v[3];
#pragma unroll
  for (int msk = 1; msk < 64; msk <<= 1) ss += __shfl_xor(ss, msk);
  __shared__ float red[4];
  if (lane == 0) red[wave] = ss;
  __syncthreads();
  ss = red[0] + red[1] + red[2] + red[3];
  float rs = rsqrtf(ss * (1.0f / TD) + 1e-6f);
  fvec4 wv = *(const fvec4*)(W + tid * 4);
  ushort4v o0, o1;
#pragma unroll
  for (int j = 0; j < 4; ++j) {
    unsigned short h, m; split2(v[j] * rs * wv[j], h, m);
    o0[j] = h; o1[j] = m;
  }
  size_t idx = (size_t)row * TD + tid * 4;
  *(ushort4v*)(O0 + idx) = o0;
  *(ushort4v*)(O1 + idx) = o1;
}

// ---------------- high-precision GEMM: A,B pre-split bf16 pairs, 3-product split.
// gload_lds staging, dbuf, SINGLE-barrier pipeline (stage-top, drain-after-compute).
// MODE 0: QKV -> scatter pairs: Q,K at [bh][s][dh]; V transposed [bh][dh][s]
// MODE 1: f32 out = acc + bias + resid
template<int MODE>
__global__ __launch_bounds__(256)
void gemm2(const unsigned short* __restrict__ A0,
           const unsigned short* __restrict__ A1,
           const unsigned short* __restrict__ B0,
           const unsigned short* __restrict__ B1,
           const float* __restrict__ bias, int Kd,
           float* __restrict__ outF, const float* __restrict__ resid,
           unsigned short* __restrict__ S0,
           unsigned short* __restrict__ S1) {
  __shared__ __align__(16) unsigned short As0[2][4096], As1[2][4096];
  __shared__ __align__(16) unsigned short Bs0[2][4096], Bs1[2][4096];
  const int tid = threadIdx.x;
  const int lane = tid & 63;
  const int w = tid >> 6;
  const int wr = w >> 1, wc = w & 1;
  const int g = lane >> 4;
  const int l15 = lane & 15;
  const int m0 = blockIdx.y * 128;
  const int n0 = blockIdx.x * 128;

  const int c_swz = (lane & 3) ^ ((lane >> 3) & 3);
  const unsigned short *a0p[2], *a1p[2], *b0p[2], *b1p[2];
  int ldsrow[2];
#pragma unroll
  for (int j = 0; j < 2; ++j) {
    int r16 = w * 2 + j;
    int r = r16 * 16 + (lane >> 2);
    a0p[j] = A0 + (size_t)(m0 + r) * Kd + c_swz * 8;
    a1p[j] = A1 + (size_t)(m0 + r) * Kd + c_swz * 8;
    b0p[j] = B0 + (size_t)(n0 + r) * Kd + c_swz * 8;
    b1p[j] = B1 + (size_t)(n0 + r) * Kd + c_swz * 8;
    ldsrow[j] = r16 * 512;
  }

#define G2_STAGE(p, koff)                              \
  {                                                    \
    _Pragma("unroll")                                  \
    for (int j = 0; j < 2; ++j) {                      \
      gload16(a0p[j] + (koff), &As0[p][ldsrow[j]]);    \
      gload16(a1p[j] + (koff), &As1[p][ldsrow[j]]);    \
      gload16(b0p[j] + (koff), &Bs0[p][ldsrow[j]]);    \
      gload16(b1p[j] + (koff), &Bs1[p][ldsrow[j]]);    \
    }                                                  \
  }

  f32x4 acc[4][4] = {};
  const int nt = Kd >> 5;

  G2_STAGE(0, 0);
  asm volatile("s_waitcnt vmcnt(0)" ::: "memory");
  __builtin_amdgcn_s_barrier();
  for (int t = 0; t < nt; ++t) {
    const int p = t & 1;
    if (t + 1 < nt) G2_STAGE(p ^ 1, (t + 1) * 32);

    short8 a0f[4], a1f[4], b0f[4], b1f[4];
#pragma unroll
    for (int mi = 0; mi < 4; ++mi) {
      int row = wr * 64 + mi * 16 + l15;
      int off = (row * 64 + g * 16) ^ (((row >> 1) & 3) << 4);
      a0f[mi] = *(const short8*)((const char*)As0[p] + off);
      a1f[mi] = *(const short8*)((const char*)As1[p] + off);
    }
#pragma unroll
    for (int ni = 0; ni < 4; ++ni) {
      int row = wc * 64 + ni * 16 + l15;
      int off = (row * 64 + g * 16) ^ (((row >> 1) & 3) << 4);
      b0f[ni] = *(const short8*)((const char*)Bs0[p] + off);
      b1f[ni] = *(const short8*)((const char*)Bs1[p] + off);
    }
#pragma unroll
    for (int mi = 0; mi < 4; ++mi)
#pragma unroll
      for (int ni = 0; ni < 4; ++ni) {
        f32x4 tacc = acc[mi][ni];
        tacc = mfma_bf16(a0f[mi], b0f[ni], tacc);
        tacc = mfma_bf16(a0f[mi], b1f[ni], tacc);
        tacc = mfma_bf16(a1f[mi], b0f[ni], tacc);
        acc[mi][ni] = tacc;
      }
    // drain next tile's loads (issued at loop top, hidden under compute), one barrier
    asm volatile("s_waitcnt vmcnt(0)" ::: "memory");
    __builtin_amdgcn_s_barrier();
  }
#undef G2_STAGE

#pragma unroll
  for (int mi = 0; mi < 4; ++mi) {
#pragma unroll
    for (int ni = 0; ni < 4; ++ni) {
      int n = n0 + wc * 64 + ni * 16 + l15;
      float bv = bias[n];
      if (MODE == 0) {
        int part = n >> 10, d = n & 1023, hh = d >> 6, dh = d & 63;
        int s0r = m0 + wr * 64 + mi * 16 + g * 4;
        int b = s0r >> 11, s_ = s0r & 2047;
        int bh = b * TH + hh;
        if (part < 2) {
          size_t base = (size_t)part * PSTR + (size_t)bh * (TS * TDH) + (size_t)s_ * TDH + dh;
#pragma unroll
          for (int r = 0; r < 4; ++r) {
            unsigned short h, m; split2(acc[mi][ni][r] + bv, h, m);
            size_t idx = base + (size_t)r * TDH;
            S0[idx] = h; S1[idx] = m;
          }
        } else {
          ushort4v o0, o1;
#pragma unroll
          for (int r = 0; r < 4; ++r) {
            unsigned short h, m; split2(acc[mi][ni][r] + bv, h, m);
            o0[r] = h; o1[r] = m;
          }
          size_t idx = 2 * (size_t)PSTR + (size_t)bh * (TS * TDH) + (size_t)dh * TS + s_;
          *(ushort4v*)(S0 + idx) = o0;
          *(ushort4v*)(S1 + idx) = o1;
        }
      } else {
#pragma unroll
        for (int r = 0; r < 4; ++r) {
          int m = m0 + wr * 64 + mi * 16 + g * 4 + r;
          size_t idx = (size_t)m * TD + n;
          outF[idx] = acc[mi][ni][r] + bv + resid[idx];
        }
      }
    }
  }
}

// ---------------- flash attention, causal, 3-product split, pre-split bf16 I/O
// 8 waves / 512 threads; ONE q-tile per block, pair-balanced mapping:
// blocks (2j,2j+1) -> qtb (j, 15-j), constant 34 kt-iters per consecutive pair.
__global__ __launch_bounds__(512, 4)
void attn2_kernel(const unsigned short* __restrict__ S0,
                  const unsigned short* __restrict__ S1,
                  unsigned short* __restrict__ A0,
                  unsigned short* __restrict__ A1) {
  __shared__ __align__(16) char Kt0[8192], Kt1[8192];
  __shared__ __align__(16) char Vt0[8192], Vt1[8192];
  __shared__ __align__(16) char Pt0[16384], Pt1[16384];

  const int tid = threadIdx.x;
  const int lane = tid & 63;
  const int wave = tid >> 6;          // 0..7
  const int g = lane >> 4, l15 = lane & 15;

  const int bh = blockIdx.y;
  const int b = bh >> 4, hh = bh & 15;

  const size_t qbase = (size_t)bh * TS * TDH;
  const size_t kbase = (size_t)PSTR + qbase;
  const size_t vbase = 2 * (size_t)PSTR + qbase;   // [dh][s] layout

  const int bx = blockIdx.x;
  const int qtb = (bx & 1) ? (15 - (bx >> 1)) : (bx >> 1);
  const int qlo = qtb * 128 + wave * 16;           // wave's first q row

  short8 aq0[2], aq1[2];
#pragma unroll
  for (int c = 0; c < 2; ++c) {
    size_t qo = qbase + (size_t)(qlo + l15) * TDH + c * 32 + g * 8;
    aq0[c] = *(const short8*)(S0 + qo);
    aq1[c] = *(const short8*)(S1 + qo);
  }

  f32x4 accv[4] = {};
  float m_[4] = {-1e30f, -1e30f, -1e30f, -1e30f};
  float l_[4] = {0.f, 0.f, 0.f, 0.f};

  const int ktmax = 2 * qtb + 1;
  for (int kt = 0; kt <= ktmax; ++kt) {
    __syncthreads();
    {
      int row = tid >> 3, ch = tid & 7;
      int off = (row * 128 + ch * 16) ^ ((row & 7) << 4);
      size_t kg = kbase + (size_t)(kt * 64 + row) * TDH + ch * 8;
      *(short8*)(Kt0 + off) = *(const short8*)(S0 + kg);
      *(short8*)(Kt1 + off) = *(const short8*)(S1 + kg);
      size_t vg = vbase + (size_t)row * TS + kt * 64 + ch * 8;
      *(short8*)(Vt0 + off) = *(const short8*)(S0 + vg);
      *(short8*)(Vt1 + off) = *(const short8*)(S1 + vg);
    }
    __syncthreads();

    if (kt * 64 > qlo + 15) continue;   // above diagonal for this wave
    const bool needmask = (kt * 64 + 63 > qlo);

    f32x4 sf[4] = {};
#pragma unroll
    for (int kb = 0; kb < 4; ++kb) {
#pragma unroll
      for (int c = 0; c < 2; ++c) {
        int krow = kb * 16 + l15;
        int off = (krow * 128 + (c * 32 + g * 8) * 2) ^ ((krow & 7) << 4);
        short8 bk0 = *(const short8*)(Kt0 + off);
        short8 bk1 = *(const short8*)(Kt1 + off);
        f32x4 t = sf[kb];
        t = mfma_bf16(aq0[c], bk0, t);
        t = mfma_bf16(aq0[c], bk1, t);
        t = mfma_bf16(aq1[c], bk0, t);
        sf[kb] = t;
      }
    }

    float pv[4][4];
#pragma unroll
    for (int r = 0; r < 4; ++r) {
      float s0 = sf[0][r] * 0.125f, s1 = sf[1][r] * 0.125f;
      float s2 = sf[2][r] * 0.125f, s3 = sf[3][r] * 0.125f;
      if (needmask) {
        int qg = qlo + g * 4 + r;
        int k0g = kt * 64 + l15;
        if (k0g      > qg) s0 = -1e30f;
        if (k0g + 16 > qg) s1 = -1e30f;
        if (k0g + 32 > qg) s2 = -1e30f;
        if (k0g + 48 > qg) s3 = -1e30f;
      }
      float mx = fmaxf(fmaxf(s0, s1), fmaxf(s2, s3));
#pragma unroll
      for (int msk = 1; msk < 16; msk <<= 1) mx = fmaxf(mx, __shfl_xor(mx, msk));
      float nm = fmaxf(m_[r], mx);
      float sc = __expf(m_[r] - nm);
      float p0 = __expf(s0 - nm), p1 = __expf(s1 - nm);
      float p2 = __expf(s2 - nm), p3 = __expf(s3 - nm);
      float rs = p0 + p1 + p2 + p3;
#pragma unroll
      for (int msk = 1; msk < 16; msk <<= 1) rs += __shfl_xor(rs, msk);
      m_[r] = nm;
      l_[r] = l_[r] * sc + rs;
#pragma unroll
      for (int dhb = 0; dhb < 4; ++dhb) accv[dhb][r] *= sc;
      pv[0][r] = p0; pv[1][r] = p1; pv[2][r] = p2; pv[3][r] = p3;
    }

    char* P0 = Pt0 + wave * 2048;
    char* P1 = Pt1 + wave * 2048;
#pragma unroll
    for (int kb = 0; kb < 4; ++kb) {
#pragma unroll
      for (int r = 0; r < 4; ++r) {
        int prow = g * 4 + r;
        int key = kb * 16 + l15;
        int off = (prow * 128 + key * 2) ^ ((prow & 7) << 4);
        unsigned short h, m; split2(pv[kb][r], h, m);
        *(unsigned short*)(P0 + off) = h;
        *(unsigned short*)(P1 + off) = m;
      }
    }
    short8 pa0[2], pa1[2];
#pragma unroll
    for (int c = 0; c < 2; ++c) {
      int off = (l15 * 128 + (c * 32 + g * 8) * 2) ^ ((l15 & 7) << 4);
      pa0[c] = *(const short8*)(P0 + off);
      pa1[c] = *(const short8*)(P1 + off);
    }
#pragma unroll
    for (int dhb = 0; dhb < 4; ++dhb) {
#pragma unroll
      for (int c = 0; c < 2; ++c) {
        int dh = dhb * 16 + l15;
        int off = (dh * 128 + (c * 32 + g * 8) * 2) ^ ((dh & 7) << 4);
        short8 bv0 = *(const short8*)(Vt0 + off);
        short8 bv1 = *(const short8*)(Vt1 + off);
        f32x4 t = accv[dhb];
        t = mfma_bf16(pa0[c], bv0, t);
        t = mfma_bf16(pa0[c], bv1, t);
        t = mfma_bf16(pa1[c], bv0, t);
        accv[dhb] = t;
      }
    }
  }

#pragma unroll
  for (int dhb = 0; dhb < 4; ++dhb) {
#pragma unroll
    for (int r = 0; r < 4; ++r) {
      int srow = qlo + g * 4 + r;
      int col = hh * 64 + dhb * 16 + l15;
      unsigned short h, m; split2(accv[dhb][r] / l_[r], h, m);
      size_t idx = ((size_t)(b * TS + srow)) * TD + col;
      A0[idx] = h; A1[idx] = m;
    }
  }
}

// ---------------- MoE token pre-gather: h2p[slot] = h2[tperm[slot]] (always 2*TT slots)
__global__ __launch_bounds__(256)
void moe_gather_kernel(const unsigned short* __restrict__ h2,
                       const int* __restrict__ tperm,
                       unsigned short* __restrict__ h2p) {
  int slot = blockIdx.x;
  int t = tperm[slot];
  const ushort4v* src = (const ushort4v*)(h2 + (size_t)t * TD);
  ushort4v* dst = (ushort4v*)(h2p + (size_t)slot * TD);
  dst[threadIdx.x] = src[threadIdx.x];
}

// ---------------- MoE GEMM (plain bf16), gload_lds + dbuf + SINGLE-barrier pipeline.
// A is packed by slot (contiguous rows) for BOTH modes.
// MODE 2: up-proj, gelu -> he bf16. (Kd == Kstride, koff = 0)
// MODE 3: down-proj SPLIT-K: blockIdx.z = e*2 + ks; each half-K writes bf16
//         gated partials to ysb[ks][slot][n] (no atomics).
template<int MODE>
__global__ __launch_bounds__(256)
void gemm_bt(const unsigned short* __restrict__ A,
             const unsigned short* __restrict__ Bt,
             const float* __restrict__ bias,
             int N, int Kd, int Kstride,
             unsigned short* __restrict__ ysb,
             unsigned short* __restrict__ outH,
             const int* __restrict__ seg_off,
             const int* __restrict__ seg_cnt,
             const float* __restrict__ gate_perm) {
  __shared__ __align__(16) unsigned short As[2][4096];   // [128][32] swizzled
  __shared__ __align__(16) unsigned short Bs[2][4096];

  const int tid = threadIdx.x;
  const int lane = tid & 63;
  const int w = tid >> 6;
  const int wr = w >> 1, wc = w & 1;
  const int g = lane >> 4;
  const int l15 = lane & 15;

  const int e  = (MODE == 3) ? ((int)blockIdx.z >> 1) : (int)blockIdx.z;
  const int ks = (MODE == 3) ? ((int)blockIdx.z & 1) : 0;
  const int koff = ks * Kd;
  const int m0 = blockIdx.y * 128;
  const int n0 = blockIdx.x * 128;
  const int off = seg_off[e];
  const int Mrows = seg_cnt[e];
  if (m0 >= Mrows) return;
  Bt += (size_t)e * N * Kstride;
  bias += (size_t)e * N;

  const int c_swz = (lane & 3) ^ ((lane >> 3) & 3);
  const unsigned short* aptr[2];
  const unsigned short* bptr[2];
  int ldsrow[2];
#pragma unroll
  for (int j = 0; j < 2; ++j) {
    int r16 = w * 2 + j;
    int r = r16 * 16 + (lane >> 2);
    int rc = (m0 + r < Mrows) ? (m0 + r) : (Mrows - 1);
    aptr[j] = A + (size_t)(off + rc) * Kstride + koff + c_swz * 8;
    bptr[j] = Bt + (size_t)(n0 + r) * Kstride + koff + c_swz * 8;
    ldsrow[j] = r16 * 512;
  }

#define GB_STAGE(p, ko)                             \
  {                                                 \
    _Pragma("unroll")                               \
    for (int j = 0; j < 2; ++j) {                   \
      gload16(aptr[j] + (ko), &As[p][ldsrow[j]]);   \
      gload16(bptr[j] + (ko), &Bs[p][ldsrow[j]]);   \
    }                                               \
  }

  f32x4 acc[4][4] = {};
  const int nt = Kd >> 5;

  GB_STAGE(0, 0);
  asm volatile("s_waitcnt vmcnt(0)" ::: "memory");
  __builtin_amdgcn_s_barrier();
  for (int t = 0; t < nt; ++t) {
    const int p = t & 1;
    if (t + 1 < nt) GB_STAGE(p ^ 1, (t + 1) * 32);

    short8 af[4], bfr[4];
#pragma unroll
    for (int mi = 0; mi < 4; ++mi) {
      int row = wr * 64 + mi * 16 + l15;
      int o2 = (row * 64 + g * 16) ^ (((row >> 1) & 3) << 4);
      af[mi] = *(const short8*)((const char*)As[p] + o2);
    }
#pragma unroll
    for (int ni = 0; ni < 4; ++ni) {
      int row = wc * 64 + ni * 16 + l15;
      int o2 = (row * 64 + g * 16) ^ (((row >> 1) & 3) << 4);
      bfr[ni] = *(const short8*)((const char*)Bs[p] + o2);
    }
#pragma unroll
    for (int mi = 0; mi < 4; ++mi)
#pragma unroll
      for (int ni = 0; ni < 4; ++ni)
        acc[mi][ni] = mfma_bf16(af[mi], bfr[ni], acc[mi][ni]);
    // drain next tile's loads (issued at loop top, hidden under compute), one barrier
    asm volatile("s_waitcnt vmcnt(0)" ::: "memory");
    __builtin_amdgcn_s_barrier();
  }
#undef GB_STAGE

#pragma unroll
  for (int mi = 0; mi < 4; ++mi) {
#pragma unroll
    for (int ni = 0; ni < 4; ++ni) {
      int n = n0 + wc * 64 + ni * 16 + l15;
      float bv = (MODE == 3 && ks != 0) ? 0.0f : bias[n];
#pragma unroll
      for (int r = 0; r < 4; ++r) {
        int mloc = m0 + wr * 64 + mi * 16 + g * 4 + r;
        if (mloc >= Mrows) continue;
        float val = acc[mi][ni][r] + bv;
        if (MODE == 2) {
          outH[(size_t)(off + mloc) * TF + n] = f2bf(gelu_f(val));
        } else {
          float gv = gate_perm[off + mloc];
          ysb[(size_t)ks * (2ull * TT * TD) + (size_t)(off + mloc) * TD + n] =
              f2bf(gv * val);
        }
      }
    }
  }
}

// ---------------- MoE reduce: out[t] += sum of 4 bf16 partials (2 slots x 2 K-halves)
__global__ __launch_bounds__(256)
void moe_reduce_kernel(const unsigned short* __restrict__ ys, const int* __restrict__ tslot,
                       float* __restrict__ out) {
  int t = blockIdx.x;
  int d = threadIdx.x * 4;
  int s0 = tslot[t * 2], s1 = tslot[t * 2 + 1];
  const unsigned short* ys1 = ys + 2ull * TT * TD;
  ushort4v a0 = *(const ushort4v*)(ys  + (size_t)s0 * TD + d);
  ushort4v a1 = *(const ushort4v*)(ys1 + (size_t)s0 * TD + d);
  ushort4v b0 = *(const ushort4v*)(ys  + (size_t)s1 * TD + d);
  ushort4v b1 = *(const ushort4v*)(ys1 + (size_t)s1 * TD + d);
  float* o = out + (size_t)t * TD + d;
  fvec4 c = *(const fvec4*)o;
#pragma unroll
  for (int j = 0; j < 4; ++j)
    c[j] += bf2f(a0[j]) + bf2f(a1[j]) + bf2f(b0[j]) + bf2f(b1[j]);
  *(fvec4*)o = c;
}

// ---------------- router: per-block LDS aggregation, 8 global atomics/block
__global__ __launch_bounds__(256)
void router_kernel(const float* __restrict__ X1, const float* __restrict__ N2W,
                   const float* __restrict__ RW, const float* __restrict__ RB,
                   int* __restrict__ top_e, float* __restrict__ top_g,
                   int* __restrict__ counts, float* __restrict__ p_sum) {
  __shared__ float s_psum[TE];
  __shared__ int s_cnt[TE];
  if (threadIdx.x < TE) { s_psum[threadIdx.x] = 0.f; s_cnt[threadIdx.x] = 0; }
  __syncthreads();
  int lane = threadIdx.x & 63, wave = threadIdx.x >> 6;
  for (int it = 0; it < 16; ++it) {
    int t = (blockIdx.x * 4 + wave) * 16 + it;
    const float* xr = X1 + (size_t)t * TD;
    float vals[16]; float ss = 0.f;
#pragma unroll
    for (int i = 0; i < 16; ++i) { float xv = xr[i * 64 + lane]; vals[i] = xv; ss += xv * xv; }
#pragma unroll
    for (int msk = 1; msk < 64; msk <<= 1) ss += __shfl_xor(ss, msk);
    float rs = rsqrtf(ss * (1.0f / TD) + 1e-6f);
    float acc[TE] = {};
#pragma unroll
    for (int i = 0; i < 16; ++i) {
      int d = i * 64 + lane;
      float nv = vals[i] * rs * N2W[d];
      const float* rwp = RW + (size_t)d * TE;
#pragma unroll
      for (int e2 = 0; e2 < TE; ++e2) acc[e2] += nv * rwp[e2];
    }
#pragma unroll
    for (int msk = 1; msk < 64; msk <<= 1)
#pragma unroll
      for (int e2 = 0; e2 < TE; ++e2) acc[e2] += __shfl_xor(acc[e2], msk);
    if (lane == 0) {
      float lg[TE]; float mx = -1e30f;
      for (int e2 = 0; e2 < TE; ++e2) { lg[e2] = acc[e2] + RB[e2]; mx = fmaxf(mx, lg[e2]); }
      float sum = 0.f, pe[TE];
      for (int e2 = 0; e2 < TE; ++e2) { pe[e2] = expf(lg[e2] - mx); sum += pe[e2]; }
      float inv = 1.0f / sum;
      for (int e2 = 0; e2 < TE; ++e2) atomicAdd(&s_psum[e2], pe[e2] * inv);
      int i1 = 0;
      for (int e2 = 1; e2 < TE; ++e2) if (lg[e2] > lg[i1]) i1 = e2;
      int i2 = (i1 == 0) ? 1 : 0;
      for (int e2 = 0; e2 < TE; ++e2) if (e2 != i1 && lg[e2] > lg[i2]) i2 = e2;
      float g1 = pe[i1], g2 = pe[i2], gs = g1 + g2;
      top_e[t * 2] = i1; top_e[t * 2 + 1] = i2;
      top_g[t * 2] = g1 / gs; top_g[t * 2 + 1] = g2 / gs;
      atomicAdd(&s_cnt[i1], 1); atomicAdd(&s_cnt[i2], 1);
    }
  }
  __syncthreads();
  if (threadIdx.x < TE) {
    atomicAdd(&p_sum[threadIdx.x], s_psum[threadIdx.x]);
    atomicAdd(&counts[threadIdx.x], s_cnt[threadIdx.x]);
  }
}

__global__ void zero_meta_kernel(int* counts, float* p_sum) {
  int t = threadIdx.x;
  if (t < TE) { counts[t] = 0; p_sum[t] = 0.f; }
}

__global__ void offsets_kernel(const int* counts, int* offs, int* cursor) {
  if (threadIdx.x == 0) {
    int o = 0;
    for (int e2 = 0; e2 < TE; ++e2) { offs[e2] = o; o += counts[e2]; }
  }
  if (threadIdx.x < TE) cursor[threadIdx.x] = 0;
}

// ---------------- fill: per-block LDS histogram + range-reserve; records slots
__global__ __launch_bounds__(256)
void fill_kernel(const int* __restrict__ top_e, const float* __restrict__ top_g,
                 const int* __restrict__ offs, int* __restrict__ cursor,
                 int* __restrict__ token_perm, float* __restrict__ gate_perm,
                 int* __restrict__ tslot) {
  __shared__ int s_cnt[TE], s_base[TE];
  if (threadIdx.x < TE) s_cnt[threadIdx.x] = 0;
  __syncthreads();
  int t = blockIdx.x * 256 + threadIdx.x;
  int e0 = top_e[t * 2], e1 = top_e[t * 2 + 1];
  int r0 = atomicAdd(&s_cnt[e0], 1);
  int r1 = atomicAdd(&s_cnt[e1], 1);
  __syncthreads();
  if (threadIdx.x < TE)
    s_base[threadIdx.x] = atomicAdd(&cursor[threadIdx.x], s_cnt[threadIdx.x]);
  __syncthreads();
  int p0 = offs[e0] + s_base[e0] + r0;
  int p1 = offs[e1] + s_base[e1] + r1;
  token_perm[p0] = t; gate_perm[p0] = top_g[t * 2];
  token_perm[p1] = t; gate_perm[p1] = top_g[t * 2 + 1];
  tslot[t * 2] = p0; tslot[t * 2 + 1] = p1;
}

__global__ void aux_kernel(const int* counts, const float* p_sum, float* outv) {
  if (threadIdx.x == 0) {
    float a = 0.f;
    for (int e2 = 0; e2 < TE; ++e2)
      a += ((float)counts[e2] / (float)TT) * (p_sum[e2] / (float)TT);
    outv[0] = (float)TE * a;
  }
}

extern "C" void kernel_launch(void* const* d_in, const int* in_sizes, int n_in,
                              void* d_out, int out_size, void* d_ws, size_t ws_size,
                              hipStream_t stream) {
  const float* x     = (const float*)d_in[0];
  const float* n1w   = (const float*)d_in[1];
  const float* n2w   = (const float*)d_in[2];
  const float* w_qkv = (const float*)d_in[3];
  const float* b_qkv = (const float*)d_in[4];
  const float* w_o   = (const float*)d_in[5];
  const float* b_o   = (const float*)d_in[6];
  const float* rw    = (const float*)d_in[7];
  const float* rb    = (const float*)d_in[8];
  const float* w1    = (const float*)d_in[9];
  const float* b1    = (const float*)d_in[10];
  const float* w2    = (const float*)d_in[11];
  const float* b2    = (const float*)d_in[12];
  float* out = (float*)d_out;
  char* ws = (char*)d_ws;

  size_t o = 0;
  auto give = [&](size_t bytes) -> char* {
    char* p = ws + o;
    o += (bytes + 255) & ~(size_t)255;
    return p;
  };
  unsigned short* w1T = (unsigned short*)give(8ull * 4096 * 1024 * 2);   // 64MB
  unsigned short* w2T = (unsigned short*)give(8ull * 1024 * 4096 * 2);   // 64MB
  unsigned short* wo0 = (unsigned short*)give(1024ull * 1024 * 2);
  unsigned short* wo1 = (unsigned short*)give(1024ull * 1024 * 2);
  unsigned short* h2  = (unsigned short*)give((size_t)TT * TD * 2);      // 8MB
  int*   counts = (int*)give(TE * 4);
  int*   cursor = (int*)give(TE * 4);
  int*   offs   = (int*)give(TE * 4);
  float* psum   = (float*)give(TE * 4);
  int*   top_e  = (int*)give(2ull * TT * 4);
  float* top_g  = (float*)give(2ull * TT * 4);
  int*   tperm  = (int*)give(2ull * TT * 4);
  float* gperm  = (float*)give(2ull * TT * 4);
  int*   tslot  = (int*)give(2ull * TT * 4);
  unsigned short* wq0 = (unsigned short*)give(3072ull * 1024 * 2);
  unsigned short* wq1 = (unsigned short*)give(3072ull * 1024 * 2);
  unsigned short* ysb = (unsigned short*)give(2ull * 2 * TT * TD * 2);   // 32MB (2 K-halves, bf16)
  // pool B: h1 pair (dead after gemm2<0>) aliased with ao pair (dead after gemm2<1>)
  // then reused as h2p packed MoE input (born after fill)
  char* poolB = give(2ull * TT * TD * 2);                                // 16MB
  unsigned short* h10 = (unsigned short*)poolB;
  unsigned short* h11 = (unsigned short*)(poolB + (size_t)TT * TD * 2);
  unsigned short* ao0 = h10; unsigned short* ao1 = h11;
  unsigned short* h2p = (unsigned short*)poolB;                          // [2TT][TD] bf16
  // pool C: qkv split pair (dead after attn) aliased with he (born at MoE up)
  char* poolC = give(64ull * 1024 * 1024);                               // 64MB
  unsigned short* qs0 = (unsigned short*)poolC;
  unsigned short* qs1 = (unsigned short*)(poolC + 3ull * PSTR * 2);
  unsigned short* he  = (unsigned short*)poolC;                          // [2TT][TF] bf16

  // weight prep
  tcvt_split_kernel<<<dim3(96, 32, 1), 256, 0, stream>>>(w_qkv, wq0, wq1, 1024, 3072);
  tcvt_split_kernel<<<dim3(32, 32, 1), 256, 0, stream>>>(w_o, wo0, wo1, 1024, 1024);
  tcvt_kernel<<<dim3(128, 32, 8), 256, 0, stream>>>(w1, w1T, 1024, 4096);
  tcvt_kernel<<<dim3(32, 128, 8), 256, 0, stream>>>(w2, w2T, 4096, 1024);

  // attention path (2-way split, 3-product; all operands pre-split)
  rmsnorm_split_kernel<<<dim3(TT), 256, 0, stream>>>(x, n1w, h10, h11);
  gemm2<0><<<dim3(24, 32, 1), 256, 0, stream>>>(
      h10, h11, wq0, wq1, b_qkv, 1024, nullptr, nullptr, qs0, qs1);
  attn2_kernel<<<dim3(16, 32, 1), 512, 0, stream>>>(qs0, qs1, ao0, ao1);
  gemm2<1><<<dim3(8, 32, 1), 256, 0, stream>>>(
      ao0, ao1, wo0, wo1, b_o, 1024, out, x, nullptr, nullptr);

  // MoE path (bf16)
  rmsnorm_kernel<<<dim3(TT), 256, 0, stream>>>(out, n2w, h2);
  zero_meta_kernel<<<dim3(1), 64, 0, stream>>>(counts, psum);
  router_kernel<<<dim3(64), 256, 0, stream>>>(out, n2w, rw, rb, top_e, top_g, counts, psum);
  offsets_kernel<<<dim3(1), 64, 0, stream>>>(counts, offs, cursor);
  fill_kernel<<<dim3(TT / 256), 256, 0, stream>>>(top_e, top_g, offs, cursor, tperm, gperm, tslot);
  moe_gather_kernel<<<dim3(2 * TT), 256, 0, stream>>>(h2, tperm, h2p);
  gemm_bt<2><<<dim3(32, 32, 8), 256, 0, stream>>>(
      h2p, w1T, b1, 4096, 1024, 1024, nullptr, he, offs, counts, gperm);
  gemm_bt<3><<<dim3(8, 32, 16), 256, 0, stream>>>(
      he, w2T, b2, 1024, 2048, 4096, ysb, nullptr, offs, counts, gperm);
  moe_reduce_kernel<<<dim3(TT), 256, 0, stream>>>(ysb, tslot, out);
  aux_kernel<<<dim3(1), 64, 0, stream>>>(counts, psum, out + (size_t)TT * TD);
}

// Round 15
// 743.959 us; speedup vs baseline: 1.0414x; 1.0414x over previous
//
#include <hip/hip_runtime.h>
#include <math.h>

#define TB 2
#define TS 2048
#define TD 1024
#define TH 16
#define TDH 64
#define TF 4096
#define TE 8
#define TT 4096                 // B*S tokens
#define PSTR (TB*TH*TS*TDH)     // 4194304 elements per q/k/v part

typedef __attribute__((ext_vector_type(8))) __bf16 bf16x8;
typedef __attribute__((ext_vector_type(4))) float f32x4;
typedef __attribute__((ext_vector_type(8))) short short8;
typedef __attribute__((ext_vector_type(4))) unsigned short ushort4v;
typedef __attribute__((ext_vector_type(4))) float fvec4;

__device__ inline unsigned short f2bf(float f) {
  union { float f; unsigned int u; } v; v.f = f;
  unsigned int u = v.u;
  unsigned int r = (u + 0x7FFFu + ((u >> 16) & 1u)) >> 16;
  return (unsigned short)r;
}
__device__ inline float bf2f(unsigned short h) {
  union { unsigned int u; float f; } v; v.u = ((unsigned int)h) << 16; return v.f;
}
// 2-way bf16 split: h+m reproduces ~17 mantissa bits (residual ~2^-18)
__device__ inline void split2(float x, unsigned short& h, unsigned short& m) {
  h = f2bf(x);
  m = f2bf(x - bf2f(h));
}

__device__ inline f32x4 mfma_bf16(short8 a, short8 b, f32x4 c) {
  return __builtin_amdgcn_mfma_f32_16x16x32_bf16(
      __builtin_bit_cast(bf16x8, a), __builtin_bit_cast(bf16x8, b), c, 0, 0, 0);
}

// async global->LDS, 16B per lane. LDS dest = wave-uniform base + lane*16.
__device__ inline void gload16(const void* g, void* l) {
  __builtin_amdgcn_global_load_lds(
      (const __attribute__((address_space(1))) void*)g,
      (__attribute__((address_space(3))) void*)l, 16, 0, 0);
}

// fast exact-GELU: erf via Abramowitz-Stegun 7.1.26 (|abs err| < 1.5e-7)
__device__ inline float gelu_f(float v) {
  float ax = fabsf(v) * 0.70710678118654752f;
  float t = __builtin_amdgcn_rcpf(1.0f + 0.3275911f * ax);
  float poly = ((((1.061405429f * t - 1.453152027f) * t + 1.421413741f) * t
                 - 0.284496736f) * t + 0.254829592f) * t;
  float er = 1.0f - poly * __expf(-ax * ax);
  er = copysignf(er, v);
  return 0.5f * v * (1.0f + er);
}

// ---------------- transpose + f32->bf16 convert: in [R,C] f32 -> out [C,R] bf16
__global__ __launch_bounds__(256)
void tcvt_kernel(const float* __restrict__ In, unsigned short* __restrict__ Out,
                 int R, int C) {
  __shared__ float tile[32][33];
  In  += (size_t)blockIdx.z * R * C;
  Out += (size_t)blockIdx.z * R * C;
  int c0 = blockIdx.x * 32, r0 = blockIdx.y * 32;
  int tx = threadIdx.x & 31, ty = threadIdx.x >> 5;  // ty 0..7
#pragma unroll
  for (int i = 0; i < 4; ++i)
    tile[ty + 8*i][tx] = In[(size_t)(r0 + ty + 8*i) * C + c0 + tx];
  __syncthreads();
#pragma unroll
  for (int i = 0; i < 4; ++i)
    Out[(size_t)(c0 + ty + 8*i) * R + r0 + tx] = f2bf(tile[tx][ty + 8*i]);
}

// ---------------- transpose + 2-way split: in [R,C] f32 -> 2x [C,R] bf16
__global__ __launch_bounds__(256)
void tcvt_split_kernel(const float* __restrict__ In,
                       unsigned short* __restrict__ O0,
                       unsigned short* __restrict__ O1, int R, int C) {
  __shared__ float tile[32][33];
  int c0 = blockIdx.x * 32, r0 = blockIdx.y * 32;
  int tx = threadIdx.x & 31, ty = threadIdx.x >> 5;
#pragma unroll
  for (int i = 0; i < 4; ++i)
    tile[ty + 8*i][tx] = In[(size_t)(r0 + ty + 8*i) * C + c0 + tx];
  __syncthreads();
#pragma unroll
  for (int i = 0; i < 4; ++i) {
    float v = tile[tx][ty + 8*i];
    unsigned short h, m; split2(v, h, m);
    size_t idx = (size_t)(c0 + ty + 8*i) * R + r0 + tx;
    O0[idx] = h; O1[idx] = m;
  }
}

// ---------------- RMSNorm f32 in -> bf16 out (for MoE expert input h2)
__global__ __launch_bounds__(256)
void rmsnorm_kernel(const float* __restrict__ X, const float* __restrict__ W,
                    unsigned short* __restrict__ O) {
  int row = blockIdx.x;
  int tid = threadIdx.x;
  int lane = tid & 63, wave = tid >> 6;
  const float* xr = X + (size_t)row * TD;
  fvec4 v = *(const fvec4*)(xr + tid * 4);
  float ss = v[0]*v[0] + v[1]*v[1] + v[2]*v[2] + v[3]*v[3];
#pragma unroll
  for (int msk = 1; msk < 64; msk <<= 1) ss += __shfl_xor(ss, msk);
  __shared__ float red[4];
  if (lane == 0) red[wave] = ss;
  __syncthreads();
  ss = red[0] + red[1] + red[2] + red[3];
  float rs = rsqrtf(ss * (1.0f / TD) + 1e-6f);
  fvec4 wv = *(const fvec4*)(W + tid * 4);
  ushort4v o;
#pragma unroll
  for (int j = 0; j < 4; ++j) o[j] = f2bf(v[j] * rs * wv[j]);
  *(ushort4v*)(O + (size_t)row * TD + tid * 4) = o;
}

// ---------------- RMSNorm f32 in -> pre-split bf16 pair (attention input h1)
__global__ __launch_bounds__(256)
void rmsnorm_split_kernel(const float* __restrict__ X, const float* __restrict__ W,
                          unsigned short* __restrict__ O0,
                          unsigned short* __restrict__ O1) {
  int row = blockIdx.x;
  int tid = threadIdx.x;
  int lane = tid & 63, wave = tid >> 6;
  const float* xr = X + (size_t)row * TD;
  fvec4 v = *(const fvec4*)(xr + tid * 4);
  float ss = v[0]*v[0] + v[1]*v[1] + v[2]*v[2] + v[3]*v[3];
#pragma unroll
  for (int msk = 1; msk < 64; msk <<= 1) ss += __shfl_xor(ss, msk);
  __shared__ float red[4];
  if (lane == 0) red[wave] = ss;
  __syncthreads();
  ss = red[0] + red[1] + red[2] + red[3];
  float rs = rsqrtf(ss * (1.0f / TD) + 1e-6f);
  fvec4 wv = *(const fvec4*)(W + tid * 4);
  ushort4v o0, o1;
#pragma unroll
  for (int j = 0; j < 4; ++j) {
    unsigned short h, m; split2(v[j] * rs * wv[j], h, m);
    o0[j] = h; o1[j] = m;
  }
  size_t idx = (size_t)row * TD + tid * 4;
  *(ushort4v*)(O0 + idx) = o0;
  *(ushort4v*)(O1 + idx) = o1;
}

// ---------------- high-precision GEMM: A,B pre-split bf16 pairs, 3-product split.
// gload_lds staging, dbuf, SINGLE-barrier pipeline (stage-top, drain-after-compute).
// MODE 0: QKV -> scatter pairs: Q,K at [bh][s][dh]; V transposed [bh][dh][s]
// MODE 1: f32 out = acc + bias + resid
template<int MODE>
__global__ __launch_bounds__(256)
void gemm2(const unsigned short* __restrict__ A0,
           const unsigned short* __restrict__ A1,
           const unsigned short* __restrict__ B0,
           const unsigned short* __restrict__ B1,
           const float* __restrict__ bias, int Kd,
           float* __restrict__ outF, const float* __restrict__ resid,
           unsigned short* __restrict__ S0,
           unsigned short* __restrict__ S1) {
  __shared__ __align__(16) unsigned short As0[2][4096], As1[2][4096];
  __shared__ __align__(16) unsigned short Bs0[2][4096], Bs1[2][4096];
  const int tid = threadIdx.x;
  const int lane = tid & 63;
  const int w = tid >> 6;
  const int wr = w >> 1, wc = w & 1;
  const int g = lane >> 4;
  const int l15 = lane & 15;
  const int m0 = blockIdx.y * 128;
  const int n0 = blockIdx.x * 128;

  const int c_swz = (lane & 3) ^ ((lane >> 3) & 3);
  const unsigned short *a0p[2], *a1p[2], *b0p[2], *b1p[2];
  int ldsrow[2];
#pragma unroll
  for (int j = 0; j < 2; ++j) {
    int r16 = w * 2 + j;
    int r = r16 * 16 + (lane >> 2);
    a0p[j] = A0 + (size_t)(m0 + r) * Kd + c_swz * 8;
    a1p[j] = A1 + (size_t)(m0 + r) * Kd + c_swz * 8;
    b0p[j] = B0 + (size_t)(n0 + r) * Kd + c_swz * 8;
    b1p[j] = B1 + (size_t)(n0 + r) * Kd + c_swz * 8;
    ldsrow[j] = r16 * 512;
  }

#define G2_STAGE(p, koff)                              \
  {                                                    \
    _Pragma("unroll")                                  \
    for (int j = 0; j < 2; ++j) {                      \
      gload16(a0p[j] + (koff), &As0[p][ldsrow[j]]);    \
      gload16(a1p[j] + (koff), &As1[p][ldsrow[j]]);    \
      gload16(b0p[j] + (koff), &Bs0[p][ldsrow[j]]);    \
      gload16(b1p[j] + (koff), &Bs1[p][ldsrow[j]]);    \
    }                                                  \
  }

  f32x4 acc[4][4] = {};
  const int nt = Kd >> 5;

  G2_STAGE(0, 0);
  asm volatile("s_waitcnt vmcnt(0)" ::: "memory");
  __builtin_amdgcn_s_barrier();
  for (int t = 0; t < nt; ++t) {
    const int p = t & 1;
    if (t + 1 < nt) G2_STAGE(p ^ 1, (t + 1) * 32);

    short8 a0f[4], a1f[4], b0f[4], b1f[4];
#pragma unroll
    for (int mi = 0; mi < 4; ++mi) {
      int row = wr * 64 + mi * 16 + l15;
      int off = (row * 64 + g * 16) ^ (((row >> 1) & 3) << 4);
      a0f[mi] = *(const short8*)((const char*)As0[p] + off);
      a1f[mi] = *(const short8*)((const char*)As1[p] + off);
    }
#pragma unroll
    for (int ni = 0; ni < 4; ++ni) {
      int row = wc * 64 + ni * 16 + l15;
      int off = (row * 64 + g * 16) ^ (((row >> 1) & 3) << 4);
      b0f[ni] = *(const short8*)((const char*)Bs0[p] + off);
      b1f[ni] = *(const short8*)((const char*)Bs1[p] + off);
    }
#pragma unroll
    for (int mi = 0; mi < 4; ++mi)
#pragma unroll
      for (int ni = 0; ni < 4; ++ni) {
        f32x4 tacc = acc[mi][ni];
        tacc = mfma_bf16(a0f[mi], b0f[ni], tacc);
        tacc = mfma_bf16(a0f[mi], b1f[ni], tacc);
        tacc = mfma_bf16(a1f[mi], b0f[ni], tacc);
        acc[mi][ni] = tacc;
      }
    // drain next tile's loads (issued at loop top, hidden under compute), one barrier
    asm volatile("s_waitcnt vmcnt(0)" ::: "memory");
    __builtin_amdgcn_s_barrier();
  }
#undef G2_STAGE

#pragma unroll
  for (int mi = 0; mi < 4; ++mi) {
#pragma unroll
    for (int ni = 0; ni < 4; ++ni) {
      int n = n0 + wc * 64 + ni * 16 + l15;
      float bv = bias[n];
      if (MODE == 0) {
        int part = n >> 10, d = n & 1023, hh = d >> 6, dh = d & 63;
        int s0r = m0 + wr * 64 + mi * 16 + g * 4;
        int b = s0r >> 11, s_ = s0r & 2047;
        int bh = b * TH + hh;
        if (part < 2) {
          size_t base = (size_t)part * PSTR + (size_t)bh * (TS * TDH) + (size_t)s_ * TDH + dh;
#pragma unroll
          for (int r = 0; r < 4; ++r) {
            unsigned short h, m; split2(acc[mi][ni][r] + bv, h, m);
            size_t idx = base + (size_t)r * TDH;
            S0[idx] = h; S1[idx] = m;
          }
        } else {
          ushort4v o0, o1;
#pragma unroll
          for (int r = 0; r < 4; ++r) {
            unsigned short h, m; split2(acc[mi][ni][r] + bv, h, m);
            o0[r] = h; o1[r] = m;
          }
          size_t idx = 2 * (size_t)PSTR + (size_t)bh * (TS * TDH) + (size_t)dh * TS + s_;
          *(ushort4v*)(S0 + idx) = o0;
          *(ushort4v*)(S1 + idx) = o1;
        }
      } else {
#pragma unroll
        for (int r = 0; r < 4; ++r) {
          int m = m0 + wr * 64 + mi * 16 + g * 4 + r;
          size_t idx = (size_t)m * TD + n;
          outF[idx] = acc[mi][ni][r] + bv + resid[idx];
        }
      }
    }
  }
}

// ---------------- flash attention, causal, 3-product split, pre-split bf16 I/O
// 8 waves / 512 threads; block handles q-tiles bx and 15-bx (heavy+light fused).
// K/V staged via global_load_lds with pre-swizzled source (linear LDS dest).
__global__ __launch_bounds__(512, 4)
void attn2_kernel(const unsigned short* __restrict__ S0,
                  const unsigned short* __restrict__ S1,
                  unsigned short* __restrict__ A0,
                  unsigned short* __restrict__ A1) {
  __shared__ __align__(16) unsigned short Kt0[4096], Kt1[4096];
  __shared__ __align__(16) unsigned short Vt0[4096], Vt1[4096];
  __shared__ __align__(16) char Pt0[16384], Pt1[16384];

  const int tid = threadIdx.x;
  const int lane = tid & 63;
  const int wave = tid >> 6;          // 0..7
  const int g = lane >> 4, l15 = lane & 15;

  const int bh = blockIdx.y;
  const int b = bh >> 4, hh = bh & 15;

  const size_t qbase = (size_t)bh * TS * TDH;
  const size_t kbase = (size_t)PSTR + qbase;
  const size_t vbase = 2 * (size_t)PSTR + qbase;   // [dh][s] layout

  // staging geometry: wave covers rows wave*8..wave*8+7 of the 64-row tile.
  // lane -> (rloc = lane>>3, phys chunk p = lane&7); source chunk = p ^ (row&7)
  // so linear LDS dest (row*128B + p*16B) holds the swizzled layout the
  // ds_read side expects: chunk at phys p is logical p ^ (row&7).
  const int srow = wave * 8 + (lane >> 3);
  const int scw = (lane & 7) ^ (srow & 7);
  unsigned short* const kdst0 = Kt0 + wave * 512;   // 8 rows * 64 elems
  unsigned short* const kdst1 = Kt1 + wave * 512;
  unsigned short* const vdst0 = Vt0 + wave * 512;
  unsigned short* const vdst1 = Vt1 + wave * 512;

  for (int half = 0; half < 2; ++half) {
    const int qtb = half ? (15 - (int)blockIdx.x) : (int)blockIdx.x;
    const int qlo = qtb * 128 + wave * 16;         // wave's first q row

    short8 aq0[2], aq1[2];
#pragma unroll
    for (int c = 0; c < 2; ++c) {
      size_t qo = qbase + (size_t)(qlo + l15) * TDH + c * 32 + g * 8;
      aq0[c] = *(const short8*)(S0 + qo);
      aq1[c] = *(const short8*)(S1 + qo);
    }

    f32x4 accv[4] = {};
    float m_[4] = {-1e30f, -1e30f, -1e30f, -1e30f};
    float l_[4] = {0.f, 0.f, 0.f, 0.f};

    const int ktmax = 2 * qtb + 1;
    for (int kt = 0; kt <= ktmax; ++kt) {
      __syncthreads();   // prior compute done reading LDS
      {
        size_t kg = kbase + (size_t)(kt * 64 + srow) * TDH + scw * 8;
        gload16(S0 + kg, kdst0);
        gload16(S1 + kg, kdst1);
        size_t vg = vbase + (size_t)srow * TS + kt * 64 + scw * 8;
        gload16(S0 + vg, vdst0);
        gload16(S1 + vg, vdst1);
      }
      __syncthreads();   // drains vmcnt(0): tile resident

      if (kt * 64 > qlo + 15) continue;   // above diagonal for this wave
      const bool needmask = (kt * 64 + 63 > qlo);

      f32x4 sf[4] = {};
      __builtin_amdgcn_s_setprio(1);
#pragma unroll
      for (int kb = 0; kb < 4; ++kb) {
#pragma unroll
        for (int c = 0; c < 2; ++c) {
          int krow = kb * 16 + l15;
          int off = (krow * 128 + (c * 32 + g * 8) * 2) ^ ((krow & 7) << 4);
          short8 bk0 = *(const short8*)((const char*)Kt0 + off);
          short8 bk1 = *(const short8*)((const char*)Kt1 + off);
          f32x4 t = sf[kb];
          t = mfma_bf16(aq0[c], bk0, t);
          t = mfma_bf16(aq0[c], bk1, t);
          t = mfma_bf16(aq1[c], bk0, t);
          sf[kb] = t;
        }
      }
      __builtin_amdgcn_s_setprio(0);

      float pv[4][4];
#pragma unroll
      for (int r = 0; r < 4; ++r) {
        float s0 = sf[0][r] * 0.125f, s1 = sf[1][r] * 0.125f;
        float s2 = sf[2][r] * 0.125f, s3 = sf[3][r] * 0.125f;
        if (needmask) {
          int qg = qlo + g * 4 + r;
          int k0g = kt * 64 + l15;
          if (k0g      > qg) s0 = -1e30f;
          if (k0g + 16 > qg) s1 = -1e30f;
          if (k0g + 32 > qg) s2 = -1e30f;
          if (k0g + 48 > qg) s3 = -1e30f;
        }
        float mx = fmaxf(fmaxf(s0, s1), fmaxf(s2, s3));
#pragma unroll
        for (int msk = 1; msk < 16; msk <<= 1) mx = fmaxf(mx, __shfl_xor(mx, msk));
        float nm = fmaxf(m_[r], mx);
        float sc = __expf(m_[r] - nm);
        float p0 = __expf(s0 - nm), p1 = __expf(s1 - nm);
        float p2 = __expf(s2 - nm), p3 = __expf(s3 - nm);
        float rs = p0 + p1 + p2 + p3;
#pragma unroll
        for (int msk = 1; msk < 16; msk <<= 1) rs += __shfl_xor(rs, msk);
        m_[r] = nm;
        l_[r] = l_[r] * sc + rs;
#pragma unroll
        for (int dhb = 0; dhb < 4; ++dhb) accv[dhb][r] *= sc;
        pv[0][r] = p0; pv[1][r] = p1; pv[2][r] = p2; pv[3][r] = p3;
      }

      char* P0 = Pt0 + wave * 2048;
      char* P1 = Pt1 + wave * 2048;
#pragma unroll
      for (int kb = 0; kb < 4; ++kb) {
#pragma unroll
        for (int r = 0; r < 4; ++r) {
          int prow = g * 4 + r;
          int key = kb * 16 + l15;
          int off = (prow * 128 + key * 2) ^ ((prow & 7) << 4);
          unsigned short h, m; split2(pv[kb][r], h, m);
          *(unsigned short*)(P0 + off) = h;
          *(unsigned short*)(P1 + off) = m;
        }
      }
      short8 pa0[2], pa1[2];
#pragma unroll
      for (int c = 0; c < 2; ++c) {
        int off = (l15 * 128 + (c * 32 + g * 8) * 2) ^ ((l15 & 7) << 4);
        pa0[c] = *(const short8*)(P0 + off);
        pa1[c] = *(const short8*)(P1 + off);
      }
      __builtin_amdgcn_s_setprio(1);
#pragma unroll
      for (int dhb = 0; dhb < 4; ++dhb) {
#pragma unroll
        for (int c = 0; c < 2; ++c) {
          int dh = dhb * 16 + l15;
          int off = (dh * 128 + (c * 32 + g * 8) * 2) ^ ((dh & 7) << 4);
          short8 bv0 = *(const short8*)((const char*)Vt0 + off);
          short8 bv1 = *(const short8*)((const char*)Vt1 + off);
          f32x4 t = accv[dhb];
          t = mfma_bf16(pa0[c], bv0, t);
          t = mfma_bf16(pa0[c], bv1, t);
          t = mfma_bf16(pa1[c], bv0, t);
          accv[dhb] = t;
        }
      }
      __builtin_amdgcn_s_setprio(0);
    }

#pragma unroll
    for (int dhb = 0; dhb < 4; ++dhb) {
#pragma unroll
      for (int r = 0; r < 4; ++r) {
        int srow2 = qlo + g * 4 + r;
        int col = hh * 64 + dhb * 16 + l15;
        unsigned short h, m; split2(accv[dhb][r] / l_[r], h, m);
        size_t idx = ((size_t)(b * TS + srow2)) * TD + col;
        A0[idx] = h; A1[idx] = m;
      }
    }
  }
}

// ---------------- MoE token pre-gather: h2p[slot] = h2[tperm[slot]] (always 2*TT slots)
__global__ __launch_bounds__(256)
void moe_gather_kernel(const unsigned short* __restrict__ h2,
                       const int* __restrict__ tperm,
                       unsigned short* __restrict__ h2p) {
  int slot = blockIdx.x;
  int t = tperm[slot];
  const ushort4v* src = (const ushort4v*)(h2 + (size_t)t * TD);
  ushort4v* dst = (ushort4v*)(h2p + (size_t)slot * TD);
  dst[threadIdx.x] = src[threadIdx.x];
}

// ---------------- MoE GEMM (plain bf16), gload_lds + dbuf + SINGLE-barrier pipeline.
// A is packed by slot (contiguous rows) for BOTH modes.
// MODE 2: up-proj, gelu -> he bf16. (Kd == Kstride, koff = 0)
// MODE 3: down-proj SPLIT-K: blockIdx.z = e*2 + ks; each half-K writes bf16
//         gated partials to ysb[ks][slot][n] (no atomics).
template<int MODE>
__global__ __launch_bounds__(256)
void gemm_bt(const unsigned short* __restrict__ A,
             const unsigned short* __restrict__ Bt,
             const float* __restrict__ bias,
             int N, int Kd, int Kstride,
             unsigned short* __restrict__ ysb,
             unsigned short* __restrict__ outH,
             const int* __restrict__ seg_off,
             const int* __restrict__ seg_cnt,
             const float* __restrict__ gate_perm) {
  __shared__ __align__(16) unsigned short As[2][4096];   // [128][32] swizzled
  __shared__ __align__(16) unsigned short Bs[2][4096];

  const int tid = threadIdx.x;
  const int lane = tid & 63;
  const int w = tid >> 6;
  const int wr = w >> 1, wc = w & 1;
  const int g = lane >> 4;
  const int l15 = lane & 15;

  const int e  = (MODE == 3) ? ((int)blockIdx.z >> 1) : (int)blockIdx.z;
  const int ks = (MODE == 3) ? ((int)blockIdx.z & 1) : 0;
  const int koff = ks * Kd;
  const int m0 = blockIdx.y * 128;
  const int n0 = blockIdx.x * 128;
  const int off = seg_off[e];
  const int Mrows = seg_cnt[e];
  if (m0 >= Mrows) return;
  Bt += (size_t)e * N * Kstride;
  bias += (size_t)e * N;

  const int c_swz = (lane & 3) ^ ((lane >> 3) & 3);
  const unsigned short* aptr[2];
  const unsigned short* bptr[2];
  int ldsrow[2];
#pragma unroll
  for (int j = 0; j < 2; ++j) {
    int r16 = w * 2 + j;
    int r = r16 * 16 + (lane >> 2);
    int rc = (m0 + r < Mrows) ? (m0 + r) : (Mrows - 1);
    aptr[j] = A + (size_t)(off + rc) * Kstride + koff + c_swz * 8;
    bptr[j] = Bt + (size_t)(n0 + r) * Kstride + koff + c_swz * 8;
    ldsrow[j] = r16 * 512;
  }

#define GB_STAGE(p, ko)                             \
  {                                                 \
    _Pragma("unroll")                               \
    for (int j = 0; j < 2; ++j) {                   \
      gload16(aptr[j] + (ko), &As[p][ldsrow[j]]);   \
      gload16(bptr[j] + (ko), &Bs[p][ldsrow[j]]);   \
    }                                               \
  }

  f32x4 acc[4][4] = {};
  const int nt = Kd >> 5;

  GB_STAGE(0, 0);
  asm volatile("s_waitcnt vmcnt(0)" ::: "memory");
  __builtin_amdgcn_s_barrier();
  for (int t = 0; t < nt; ++t) {
    const int p = t & 1;
    if (t + 1 < nt) GB_STAGE(p ^ 1, (t + 1) * 32);

    short8 af[4], bfr[4];
#pragma unroll
    for (int mi = 0; mi < 4; ++mi) {
      int row = wr * 64 + mi * 16 + l15;
      int o2 = (row * 64 + g * 16) ^ (((row >> 1) & 3) << 4);
      af[mi] = *(const short8*)((const char*)As[p] + o2);
    }
#pragma unroll
    for (int ni = 0; ni < 4; ++ni) {
      int row = wc * 64 + ni * 16 + l15;
      int o2 = (row * 64 + g * 16) ^ (((row >> 1) & 3) << 4);
      bfr[ni] = *(const short8*)((const char*)Bs[p] + o2);
    }
#pragma unroll
    for (int mi = 0; mi < 4; ++mi)
#pragma unroll
      for (int ni = 0; ni < 4; ++ni)
        acc[mi][ni] = mfma_bf16(af[mi], bfr[ni], acc[mi][ni]);
    // drain next tile's loads (issued at loop top, hidden under compute), one barrier
    asm volatile("s_waitcnt vmcnt(0)" ::: "memory");
    __builtin_amdgcn_s_barrier();
  }
#undef GB_STAGE

#pragma unroll
  for (int mi = 0; mi < 4; ++mi) {
#pragma unroll
    for (int ni = 0; ni < 4; ++ni) {
      int n = n0 + wc * 64 + ni * 16 + l15;
      float bv = (MODE == 3 && ks != 0) ? 0.0f : bias[n];
#pragma unroll
      for (int r = 0; r < 4; ++r) {
        int mloc = m0 + wr * 64 + mi * 16 + g * 4 + r;
        if (mloc >= Mrows) continue;
        float val = acc[mi][ni][r] + bv;
        if (MODE == 2) {
          outH[(size_t)(off + mloc) * TF + n] = f2bf(gelu_f(val));
        } else {
          float gv = gate_perm[off + mloc];
          ysb[(size_t)ks * (2ull * TT * TD) + (size_t)(off + mloc) * TD + n] =
              f2bf(gv * val);
        }
      }
    }
  }
}

// ---------------- MoE reduce: out[t] += sum of 4 bf16 partials (2 slots x 2 K-halves)
__global__ __launch_bounds__(256)
void moe_reduce_kernel(const unsigned short* __restrict__ ys, const int* __restrict__ tslot,
                       float* __restrict__ out) {
  int t = blockIdx.x;
  int d = threadIdx.x * 4;
  int s0 = tslot[t * 2], s1 = tslot[t * 2 + 1];
  const unsigned short* ys1 = ys + 2ull * TT * TD;
  ushort4v a0 = *(const ushort4v*)(ys  + (size_t)s0 * TD + d);
  ushort4v a1 = *(const ushort4v*)(ys1 + (size_t)s0 * TD + d);
  ushort4v b0 = *(const ushort4v*)(ys  + (size_t)s1 * TD + d);
  ushort4v b1 = *(const ushort4v*)(ys1 + (size_t)s1 * TD + d);
  float* o = out + (size_t)t * TD + d;
  fvec4 c = *(const fvec4*)o;
#pragma unroll
  for (int j = 0; j < 4; ++j)
    c[j] += bf2f(a0[j]) + bf2f(a1[j]) + bf2f(b0[j]) + bf2f(b1[j]);
  *(fvec4*)o = c;
}

// ---------------- router: per-block LDS aggregation, 8 global atomics/block
__global__ __launch_bounds__(256)
void router_kernel(const float* __restrict__ X1, const float* __restrict__ N2W,
                   const float* __restrict__ RW, const float* __restrict__ RB,
                   int* __restrict__ top_e, float* __restrict__ top_g,
                   int* __restrict__ counts, float* __restrict__ p_sum) {
  __shared__ float s_psum[TE];
  __shared__ int s_cnt[TE];
  if (threadIdx.x < TE) { s_psum[threadIdx.x] = 0.f; s_cnt[threadIdx.x] = 0; }
  __syncthreads();
  int lane = threadIdx.x & 63, wave = threadIdx.x >> 6;
  for (int it = 0; it < 16; ++it) {
    int t = (blockIdx.x * 4 + wave) * 16 + it;
    const float* xr = X1 + (size_t)t * TD;
    float vals[16]; float ss = 0.f;
#pragma unroll
    for (int i = 0; i < 16; ++i) { float xv = xr[i * 64 + lane]; vals[i] = xv; ss += xv * xv; }
#pragma unroll
    for (int msk = 1; msk < 64; msk <<= 1) ss += __shfl_xor(ss, msk);
    float rs = rsqrtf(ss * (1.0f / TD) + 1e-6f);
    float acc[TE] = {};
#pragma unroll
    for (int i = 0; i < 16; ++i) {
      int d = i * 64 + lane;
      float nv = vals[i] * rs * N2W[d];
      const float* rwp = RW + (size_t)d * TE;
#pragma unroll
      for (int e2 = 0; e2 < TE; ++e2) acc[e2] += nv * rwp[e2];
    }
#pragma unroll
    for (int msk = 1; msk < 64; msk <<= 1)
#pragma unroll
      for (int e2 = 0; e2 < TE; ++e2) acc[e2] += __shfl_xor(acc[e2], msk);
    if (lane == 0) {
      float lg[TE]; float mx = -1e30f;
      for (int e2 = 0; e2 < TE; ++e2) { lg[e2] = acc[e2] + RB[e2]; mx = fmaxf(mx, lg[e2]); }
      float sum = 0.f, pe[TE];
      for (int e2 = 0; e2 < TE; ++e2) { pe[e2] = expf(lg[e2] - mx); sum += pe[e2]; }
      float inv = 1.0f / sum;
      for (int e2 = 0; e2 < TE; ++e2) atomicAdd(&s_psum[e2], pe[e2] * inv);
      int i1 = 0;
      for (int e2 = 1; e2 < TE; ++e2) if (lg[e2] > lg[i1]) i1 = e2;
      int i2 = (i1 == 0) ? 1 : 0;
      for (int e2 = 0; e2 < TE; ++e2) if (e2 != i1 && lg[e2] > lg[i2]) i2 = e2;
      float g1 = pe[i1], g2 = pe[i2], gs = g1 + g2;
      top_e[t * 2] = i1; top_e[t * 2 + 1] = i2;
      top_g[t * 2] = g1 / gs; top_g[t * 2 + 1] = g2 / gs;
      atomicAdd(&s_cnt[i1], 1); atomicAdd(&s_cnt[i2], 1);
    }
  }
  __syncthreads();
  if (threadIdx.x < TE) {
    atomicAdd(&p_sum[threadIdx.x], s_psum[threadIdx.x]);
    atomicAdd(&counts[threadIdx.x], s_cnt[threadIdx.x]);
  }
}

__global__ void zero_meta_kernel(int* counts, float* p_sum) {
  int t = threadIdx.x;
  if (t < TE) { counts[t] = 0; p_sum[t] = 0.f; }
}

__global__ void offsets_kernel(const int* counts, int* offs, int* cursor) {
  if (threadIdx.x == 0) {
    int o = 0;
    for (int e2 = 0; e2 < TE; ++e2) { offs[e2] = o; o += counts[e2]; }
  }
  if (threadIdx.x < TE) cursor[threadIdx.x] = 0;
}

// ---------------- fill: per-block LDS histogram + range-reserve; records slots
__global__ __launch_bounds__(256)
void fill_kernel(const int* __restrict__ top_e, const float* __restrict__ top_g,
                 const int* __restrict__ offs, int* __restrict__ cursor,
                 int* __restrict__ token_perm, float* __restrict__ gate_perm,
                 int* __restrict__ tslot) {
  __shared__ int s_cnt[TE], s_base[TE];
  if (threadIdx.x < TE) s_cnt[threadIdx.x] = 0;
  __syncthreads();
  int t = blockIdx.x * 256 + threadIdx.x;
  int e0 = top_e[t * 2], e1 = top_e[t * 2 + 1];
  int r0 = atomicAdd(&s_cnt[e0], 1);
  int r1 = atomicAdd(&s_cnt[e1], 1);
  __syncthreads();
  if (threadIdx.x < TE)
    s_base[threadIdx.x] = atomicAdd(&cursor[threadIdx.x], s_cnt[threadIdx.x]);
  __syncthreads();
  int p0 = offs[e0] + s_base[e0] + r0;
  int p1 = offs[e1] + s_base[e1] + r1;
  token_perm[p0] = t; gate_perm[p0] = top_g[t * 2];
  token_perm[p1] = t; gate_perm[p1] = top_g[t * 2 + 1];
  tslot[t * 2] = p0; tslot[t * 2 + 1] = p1;
}

__global__ void aux_kernel(const int* counts, const float* p_sum, float* outv) {
  if (threadIdx.x == 0) {
    float a = 0.f;
    for (int e2 = 0; e2 < TE; ++e2)
      a += ((float)counts[e2] / (float)TT) * (p_sum[e2] / (float)TT);
    outv[0] = (float)TE * a;
  }
}

extern "C" void kernel_launch(void* const* d_in, const int* in_sizes, int n_in,
                              void* d_out, int out_size, void* d_ws, size_t ws_size,
                              hipStream_t stream) {
  const float* x     = (const float*)d_in[0];
  const float* n1w   = (const float*)d_in[1];
  const float* n2w   = (const float*)d_in[2];
  const float* w_qkv = (const float*)d_in[3];
  const float* b_qkv = (const float*)d_in[4];
  const float* w_o   = (const float*)d_in[5];
  const float* b_o   = (const float*)d_in[6];
  const float* rw    = (const float*)d_in[7];
  const float* rb    = (const float*)d_in[8];
  const float* w1    = (const float*)d_in[9];
  const float* b1    = (const float*)d_in[10];
  const float* w2    = (const float*)d_in[11];
  const float* b2    = (const float*)d_in[12];
  float* out = (float*)d_out;
  char* ws = (char*)d_ws;

  size_t o = 0;
  auto give = [&](size_t bytes) -> char* {
    char* p = ws + o;
    o += (bytes + 255) & ~(size_t)255;
    return p;
  };
  unsigned short* w1T = (unsigned short*)give(8ull * 4096 * 1024 * 2);   // 64MB
  unsigned short* w2T = (unsigned short*)give(8ull * 1024 * 4096 * 2);   // 64MB
  unsigned short* wo0 = (unsigned short*)give(1024ull * 1024 * 2);
  unsigned short* wo1 = (unsigned short*)give(1024ull * 1024 * 2);
  unsigned short* h2  = (unsigned short*)give((size_t)TT * TD * 2);      // 8MB
  int*   counts = (int*)give(TE * 4);
  int*   cursor = (int*)give(TE * 4);
  int*   offs   = (int*)give(TE * 4);
  float* psum   = (float*)give(TE * 4);
  int*   top_e  = (int*)give(2ull * TT * 4);
  float* top_g  = (float*)give(2ull * TT * 4);
  int*   tperm  = (int*)give(2ull * TT * 4);
  float* gperm  = (float*)give(2ull * TT * 4);
  int*   tslot  = (int*)give(2ull * TT * 4);
  unsigned short* wq0 = (unsigned short*)give(3072ull * 1024 * 2);
  unsigned short* wq1 = (unsigned short*)give(3072ull * 1024 * 2);
  unsigned short* ysb = (unsigned short*)give(2ull * 2 * TT * TD * 2);   // 32MB (2 K-halves, bf16)
  // pool B: h1 pair (dead after gemm2<0>) aliased with ao pair (dead after gemm2<1>)
  // then reused as h2p packed MoE input (born after fill)
  char* poolB = give(2ull * TT * TD * 2);                                // 16MB
  unsigned short* h10 = (unsigned short*)poolB;
  unsigned short* h11 = (unsigned short*)(poolB + (size_t)TT * TD * 2);
  unsigned short* ao0 = h10; unsigned short* ao1 = h11;
  unsigned short* h2p = (unsigned short*)poolB;                          // [2TT][TD] bf16
  // pool C: qkv split pair (dead after attn) aliased with he (born at MoE up)
  char* poolC = give(64ull * 1024 * 1024);                               // 64MB
  unsigned short* qs0 = (unsigned short*)poolC;
  unsigned short* qs1 = (unsigned short*)(poolC + 3ull * PSTR * 2);
  unsigned short* he  = (unsigned short*)poolC;                          // [2TT][TF] bf16

  // weight prep
  tcvt_split_kernel<<<dim3(96, 32, 1), 256, 0, stream>>>(w_qkv, wq0, wq1, 1024, 3072);
  tcvt_split_kernel<<<dim3(32, 32, 1), 256, 0, stream>>>(w_o, wo0, wo1, 1024, 1024);
  tcvt_kernel<<<dim3(128, 32, 8), 256, 0, stream>>>(w1, w1T, 1024, 4096);
  tcvt_kernel<<<dim3(32, 128, 8), 256, 0, stream>>>(w2, w2T, 4096, 1024);

  // attention path (2-way split, 3-product; all operands pre-split)
  rmsnorm_split_kernel<<<dim3(TT), 256, 0, stream>>>(x, n1w, h10, h11);
  gemm2<0><<<dim3(24, 32, 1), 256, 0, stream>>>(
      h10, h11, wq0, wq1, b_qkv, 1024, nullptr, nullptr, qs0, qs1);
  attn2_kernel<<<dim3(8, 32, 1), 512, 0, stream>>>(qs0, qs1, ao0, ao1);
  gemm2<1><<<dim3(8, 32, 1), 256, 0, stream>>>(
      ao0, ao1, wo0, wo1, b_o, 1024, out, x, nullptr, nullptr);

  // MoE path (bf16)
  rmsnorm_kernel<<<dim3(TT), 256, 0, stream>>>(out, n2w, h2);
  zero_meta_kernel<<<dim3(1), 64, 0, stream>>>(counts, psum);
  router_kernel<<<dim3(64), 256, 0, stream>>>(out, n2w, rw, rb, top_e, top_g, counts, psum);
  offsets_kernel<<<dim3(1), 64, 0, stream>>>(counts, offs, cursor);
  fill_kernel<<<dim3(TT / 256), 256, 0, stream>>>(top_e, top_g, offs, cursor, tperm, gperm, tslot);
  moe_gather_kernel<<<dim3(2 * TT), 256, 0, stream>>>(h2, tperm, h2p);
  gemm_bt<2><<<dim3(32, 32, 8), 256, 0, stream>>>(
      h2p, w1T, b1, 4096, 1024, 1024, nullptr, he, offs, counts, gperm);
  gemm_bt<3><<<dim3(8, 32, 16), 256, 0, stream>>>(
      he, w2T, b2, 1024, 2048, 4096, ysb, nullptr, offs, counts, gperm);
  moe_reduce_kernel<<<dim3(TT), 256, 0, stream>>>(ysb, tslot, out);
  aux_kernel<<<dim3(1), 64, 0, stream>>>(counts, psum, out + (size_t)TT * TD);
}

// Round 16
// 733.324 us; speedup vs baseline: 1.0565x; 1.0145x over previous
//
#include <hip/hip_runtime.h>
#include <math.h>

#define TB 2
#define TS 2048
#define TD 1024
#define TH 16
#define TDH 64
#define TF 4096
#define TE 8
#define TT 4096                 // B*S tokens
#define PSTR (TB*TH*TS*TDH)     // 4194304 elements per q/k/v part

typedef __attribute__((ext_vector_type(8))) __bf16 bf16x8;
typedef __attribute__((ext_vector_type(4))) float f32x4;
typedef __attribute__((ext_vector_type(8))) short short8;
typedef __attribute__((ext_vector_type(4))) unsigned short ushort4v;
typedef __attribute__((ext_vector_type(4))) float fvec4;

__device__ inline unsigned short f2bf(float f) {
  union { float f; unsigned int u; } v; v.f = f;
  unsigned int u = v.u;
  unsigned int r = (u + 0x7FFFu + ((u >> 16) & 1u)) >> 16;
  return (unsigned short)r;
}
__device__ inline float bf2f(unsigned short h) {
  union { unsigned int u; float f; } v; v.u = ((unsigned int)h) << 16; return v.f;
}
// 2-way bf16 split: h+m reproduces ~17 mantissa bits (residual ~2^-18)
__device__ inline void split2(float x, unsigned short& h, unsigned short& m) {
  h = f2bf(x);
  m = f2bf(x - bf2f(h));
}

__device__ inline f32x4 mfma_bf16(short8 a, short8 b, f32x4 c) {
  return __builtin_amdgcn_mfma_f32_16x16x32_bf16(
      __builtin_bit_cast(bf16x8, a), __builtin_bit_cast(bf16x8, b), c, 0, 0, 0);
}

// async global->LDS, 16B per lane. LDS dest = wave-uniform base + lane*16.
__device__ inline void gload16(const void* g, void* l) {
  __builtin_amdgcn_global_load_lds(
      (const __attribute__((address_space(1))) void*)g,
      (__attribute__((address_space(3))) void*)l, 16, 0, 0);
}

// fast exact-GELU: erf via Abramowitz-Stegun 7.1.26 (|abs err| < 1.5e-7)
__device__ inline float gelu_f(float v) {
  float ax = fabsf(v) * 0.70710678118654752f;
  float t = __builtin_amdgcn_rcpf(1.0f + 0.3275911f * ax);
  float poly = ((((1.061405429f * t - 1.453152027f) * t + 1.421413741f) * t
                 - 0.284496736f) * t + 0.254829592f) * t;
  float er = 1.0f - poly * __expf(-ax * ax);
  er = copysignf(er, v);
  return 0.5f * v * (1.0f + er);
}

// ---------------- transpose + f32->bf16 convert: in [R,C] f32 -> out [C,R] bf16
__global__ __launch_bounds__(256)
void tcvt_kernel(const float* __restrict__ In, unsigned short* __restrict__ Out,
                 int R, int C) {
  __shared__ float tile[32][33];
  In  += (size_t)blockIdx.z * R * C;
  Out += (size_t)blockIdx.z * R * C;
  int c0 = blockIdx.x * 32, r0 = blockIdx.y * 32;
  int tx = threadIdx.x & 31, ty = threadIdx.x >> 5;  // ty 0..7
#pragma unroll
  for (int i = 0; i < 4; ++i)
    tile[ty + 8*i][tx] = In[(size_t)(r0 + ty + 8*i) * C + c0 + tx];
  __syncthreads();
#pragma unroll
  for (int i = 0; i < 4; ++i)
    Out[(size_t)(c0 + ty + 8*i) * R + r0 + tx] = f2bf(tile[tx][ty + 8*i]);
}

// ---------------- transpose + 2-way split: in [R,C] f32 -> 2x [C,R] bf16
__global__ __launch_bounds__(256)
void tcvt_split_kernel(const float* __restrict__ In,
                       unsigned short* __restrict__ O0,
                       unsigned short* __restrict__ O1, int R, int C) {
  __shared__ float tile[32][33];
  int c0 = blockIdx.x * 32, r0 = blockIdx.y * 32;
  int tx = threadIdx.x & 31, ty = threadIdx.x >> 5;
#pragma unroll
  for (int i = 0; i < 4; ++i)
    tile[ty + 8*i][tx] = In[(size_t)(r0 + ty + 8*i) * C + c0 + tx];
  __syncthreads();
#pragma unroll
  for (int i = 0; i < 4; ++i) {
    float v = tile[tx][ty + 8*i];
    unsigned short h, m; split2(v, h, m);
    size_t idx = (size_t)(c0 + ty + 8*i) * R + r0 + tx;
    O0[idx] = h; O1[idx] = m;
  }
}

// ---------------- RMSNorm f32 in -> pre-split bf16 pair (attention input h1)
__global__ __launch_bounds__(256)
void rmsnorm_split_kernel(const float* __restrict__ X, const float* __restrict__ W,
                          unsigned short* __restrict__ O0,
                          unsigned short* __restrict__ O1) {
  int row = blockIdx.x;
  int tid = threadIdx.x;
  int lane = tid & 63, wave = tid >> 6;
  const float* xr = X + (size_t)row * TD;
  fvec4 v = *(const fvec4*)(xr + tid * 4);
  float ss = v[0]*v[0] + v[1]*v[1] + v[2]*v[2] + v[3]*v[3];
#pragma unroll
  for (int msk = 1; msk < 64; msk <<= 1) ss += __shfl_xor(ss, msk);
  __shared__ float red[4];
  if (lane == 0) red[wave] = ss;
  __syncthreads();
  ss = red[0] + red[1] + red[2] + red[3];
  float rs = rsqrtf(ss * (1.0f / TD) + 1e-6f);
  fvec4 wv = *(const fvec4*)(W + tid * 4);
  ushort4v o0, o1;
#pragma unroll
  for (int j = 0; j < 4; ++j) {
    unsigned short h, m; split2(v[j] * rs * wv[j], h, m);
    o0[j] = h; o1[j] = m;
  }
  size_t idx = (size_t)row * TD + tid * 4;
  *(ushort4v*)(O0 + idx) = o0;
  *(ushort4v*)(O1 + idx) = o1;
}

// ---------------- high-precision GEMM: A,B pre-split bf16 pairs, 3-product split.
// gload_lds staging, dbuf, SINGLE-barrier pipeline (stage-top, drain-after-compute).
// MODE 0: QKV -> scatter pairs: Q,K at [bh][s][dh]; V transposed [bh][dh][s]
// MODE 1: f32 out = acc + bias + resid
template<int MODE>
__global__ __launch_bounds__(256)
void gemm2(const unsigned short* __restrict__ A0,
           const unsigned short* __restrict__ A1,
           const unsigned short* __restrict__ B0,
           const unsigned short* __restrict__ B1,
           const float* __restrict__ bias, int Kd,
           float* __restrict__ outF, const float* __restrict__ resid,
           unsigned short* __restrict__ S0,
           unsigned short* __restrict__ S1) {
  __shared__ __align__(16) unsigned short As0[2][4096], As1[2][4096];
  __shared__ __align__(16) unsigned short Bs0[2][4096], Bs1[2][4096];
  const int tid = threadIdx.x;
  const int lane = tid & 63;
  const int w = tid >> 6;
  const int wr = w >> 1, wc = w & 1;
  const int g = lane >> 4;
  const int l15 = lane & 15;
  const int m0 = blockIdx.y * 128;
  const int n0 = blockIdx.x * 128;

  const int c_swz = (lane & 3) ^ ((lane >> 3) & 3);
  const unsigned short *a0p[2], *a1p[2], *b0p[2], *b1p[2];
  int ldsrow[2];
#pragma unroll
  for (int j = 0; j < 2; ++j) {
    int r16 = w * 2 + j;
    int r = r16 * 16 + (lane >> 2);
    a0p[j] = A0 + (size_t)(m0 + r) * Kd + c_swz * 8;
    a1p[j] = A1 + (size_t)(m0 + r) * Kd + c_swz * 8;
    b0p[j] = B0 + (size_t)(n0 + r) * Kd + c_swz * 8;
    b1p[j] = B1 + (size_t)(n0 + r) * Kd + c_swz * 8;
    ldsrow[j] = r16 * 512;
  }

#define G2_STAGE(p, koff)                              \
  {                                                    \
    _Pragma("unroll")                                  \
    for (int j = 0; j < 2; ++j) {                      \
      gload16(a0p[j] + (koff), &As0[p][ldsrow[j]]);    \
      gload16(a1p[j] + (koff), &As1[p][ldsrow[j]]);    \
      gload16(b0p[j] + (koff), &Bs0[p][ldsrow[j]]);    \
      gload16(b1p[j] + (koff), &Bs1[p][ldsrow[j]]);    \
    }                                                  \
  }

  f32x4 acc[4][4] = {};
  const int nt = Kd >> 5;

  G2_STAGE(0, 0);
  asm volatile("s_waitcnt vmcnt(0)" ::: "memory");
  __builtin_amdgcn_s_barrier();
  for (int t = 0; t < nt; ++t) {
    const int p = t & 1;
    if (t + 1 < nt) G2_STAGE(p ^ 1, (t + 1) * 32);

    short8 a0f[4], a1f[4], b0f[4], b1f[4];
#pragma unroll
    for (int mi = 0; mi < 4; ++mi) {
      int row = wr * 64 + mi * 16 + l15;
      int off = (row * 64 + g * 16) ^ (((row >> 1) & 3) << 4);
      a0f[mi] = *(const short8*)((const char*)As0[p] + off);
      a1f[mi] = *(const short8*)((const char*)As1[p] + off);
    }
#pragma unroll
    for (int ni = 0; ni < 4; ++ni) {
      int row = wc * 64 + ni * 16 + l15;
      int off = (row * 64 + g * 16) ^ (((row >> 1) & 3) << 4);
      b0f[ni] = *(const short8*)((const char*)Bs0[p] + off);
      b1f[ni] = *(const short8*)((const char*)Bs1[p] + off);
    }
#pragma unroll
    for (int mi = 0; mi < 4; ++mi)
#pragma unroll
      for (int ni = 0; ni < 4; ++ni) {
        f32x4 tacc = acc[mi][ni];
        tacc = mfma_bf16(a0f[mi], b0f[ni], tacc);
        tacc = mfma_bf16(a0f[mi], b1f[ni], tacc);
        tacc = mfma_bf16(a1f[mi], b0f[ni], tacc);
        acc[mi][ni] = tacc;
      }
    // drain next tile's loads (issued at loop top, hidden under compute), one barrier
    asm volatile("s_waitcnt vmcnt(0)" ::: "memory");
    __builtin_amdgcn_s_barrier();
  }
#undef G2_STAGE

#pragma unroll
  for (int mi = 0; mi < 4; ++mi) {
#pragma unroll
    for (int ni = 0; ni < 4; ++ni) {
      int n = n0 + wc * 64 + ni * 16 + l15;
      float bv = bias[n];
      if (MODE == 0) {
        int part = n >> 10, d = n & 1023, hh = d >> 6, dh = d & 63;
        int s0r = m0 + wr * 64 + mi * 16 + g * 4;
        int b = s0r >> 11, s_ = s0r & 2047;
        int bh = b * TH + hh;
        if (part < 2) {
          size_t base = (size_t)part * PSTR + (size_t)bh * (TS * TDH) + (size_t)s_ * TDH + dh;
#pragma unroll
          for (int r = 0; r < 4; ++r) {
            unsigned short h, m; split2(acc[mi][ni][r] + bv, h, m);
            size_t idx = base + (size_t)r * TDH;
            S0[idx] = h; S1[idx] = m;
          }
        } else {
          ushort4v o0, o1;
#pragma unroll
          for (int r = 0; r < 4; ++r) {
            unsigned short h, m; split2(acc[mi][ni][r] + bv, h, m);
            o0[r] = h; o1[r] = m;
          }
          size_t idx = 2 * (size_t)PSTR + (size_t)bh * (TS * TDH) + (size_t)dh * TS + s_;
          *(ushort4v*)(S0 + idx) = o0;
          *(ushort4v*)(S1 + idx) = o1;
        }
      } else {
#pragma unroll
        for (int r = 0; r < 4; ++r) {
          int m = m0 + wr * 64 + mi * 16 + g * 4 + r;
          size_t idx = (size_t)m * TD + n;
          outF[idx] = acc[mi][ni][r] + bv + resid[idx];
        }
      }
    }
  }
}

// ---------------- flash attention, causal, 3-product split, pre-split bf16 I/O
// 8 waves / 512 threads; block handles q-tiles bx and 15-bx (heavy+light fused).
// K/V staged via global_load_lds with pre-swizzled source (linear LDS dest).
__global__ __launch_bounds__(512, 4)
void attn2_kernel(const unsigned short* __restrict__ S0,
                  const unsigned short* __restrict__ S1,
                  unsigned short* __restrict__ A0,
                  unsigned short* __restrict__ A1) {
  __shared__ __align__(16) unsigned short Kt0[4096], Kt1[4096];
  __shared__ __align__(16) unsigned short Vt0[4096], Vt1[4096];
  __shared__ __align__(16) char Pt0[16384], Pt1[16384];

  const int tid = threadIdx.x;
  const int lane = tid & 63;
  const int wave = tid >> 6;          // 0..7
  const int g = lane >> 4, l15 = lane & 15;

  const int bh = blockIdx.y;
  const int b = bh >> 4, hh = bh & 15;

  const size_t qbase = (size_t)bh * TS * TDH;
  const size_t kbase = (size_t)PSTR + qbase;
  const size_t vbase = 2 * (size_t)PSTR + qbase;   // [dh][s] layout

  const int srow = wave * 8 + (lane >> 3);
  const int scw = (lane & 7) ^ (srow & 7);
  unsigned short* const kdst0 = Kt0 + wave * 512;   // 8 rows * 64 elems
  unsigned short* const kdst1 = Kt1 + wave * 512;
  unsigned short* const vdst0 = Vt0 + wave * 512;
  unsigned short* const vdst1 = Vt1 + wave * 512;

  for (int half = 0; half < 2; ++half) {
    const int qtb = half ? (15 - (int)blockIdx.x) : (int)blockIdx.x;
    const int qlo = qtb * 128 + wave * 16;         // wave's first q row

    short8 aq0[2], aq1[2];
#pragma unroll
    for (int c = 0; c < 2; ++c) {
      size_t qo = qbase + (size_t)(qlo + l15) * TDH + c * 32 + g * 8;
      aq0[c] = *(const short8*)(S0 + qo);
      aq1[c] = *(const short8*)(S1 + qo);
    }

    f32x4 accv[4] = {};
    float m_[4] = {-1e30f, -1e30f, -1e30f, -1e30f};
    float l_[4] = {0.f, 0.f, 0.f, 0.f};

    const int ktmax = 2 * qtb + 1;
    for (int kt = 0; kt <= ktmax; ++kt) {
      __syncthreads();   // prior compute done reading LDS
      {
        size_t kg = kbase + (size_t)(kt * 64 + srow) * TDH + scw * 8;
        gload16(S0 + kg, kdst0);
        gload16(S1 + kg, kdst1);
        size_t vg = vbase + (size_t)srow * TS + kt * 64 + scw * 8;
        gload16(S0 + vg, vdst0);
        gload16(S1 + vg, vdst1);
      }
      __syncthreads();   // drains vmcnt(0): tile resident

      if (kt * 64 > qlo + 15) continue;   // above diagonal for this wave
      const bool needmask = (kt * 64 + 63 > qlo);

      f32x4 sf[4] = {};
      __builtin_amdgcn_s_setprio(1);
#pragma unroll
      for (int kb = 0; kb < 4; ++kb) {
#pragma unroll
        for (int c = 0; c < 2; ++c) {
          int krow = kb * 16 + l15;
          int off = (krow * 128 + (c * 32 + g * 8) * 2) ^ ((krow & 7) << 4);
          short8 bk0 = *(const short8*)((const char*)Kt0 + off);
          short8 bk1 = *(const short8*)((const char*)Kt1 + off);
          f32x4 t = sf[kb];
          t = mfma_bf16(aq0[c], bk0, t);
          t = mfma_bf16(aq0[c], bk1, t);
          t = mfma_bf16(aq1[c], bk0, t);
          sf[kb] = t;
        }
      }
      __builtin_amdgcn_s_setprio(0);

      float pv[4][4];
#pragma unroll
      for (int r = 0; r < 4; ++r) {
        float s0 = sf[0][r] * 0.125f, s1 = sf[1][r] * 0.125f;
        float s2 = sf[2][r] * 0.125f, s3 = sf[3][r] * 0.125f;
        if (needmask) {
          int qg = qlo + g * 4 + r;
          int k0g = kt * 64 + l15;
          if (k0g      > qg) s0 = -1e30f;
          if (k0g + 16 > qg) s1 = -1e30f;
          if (k0g + 32 > qg) s2 = -1e30f;
          if (k0g + 48 > qg) s3 = -1e30f;
        }
        float mx = fmaxf(fmaxf(s0, s1), fmaxf(s2, s3));
#pragma unroll
        for (int msk = 1; msk < 16; msk <<= 1) mx = fmaxf(mx, __shfl_xor(mx, msk));
        float nm = fmaxf(m_[r], mx);
        float sc = __expf(m_[r] - nm);
        float p0 = __expf(s0 - nm), p1 = __expf(s1 - nm);
        float p2 = __expf(s2 - nm), p3 = __expf(s3 - nm);
        float rs = p0 + p1 + p2 + p3;
#pragma unroll
        for (int msk = 1; msk < 16; msk <<= 1) rs += __shfl_xor(rs, msk);
        m_[r] = nm;
        l_[r] = l_[r] * sc + rs;
#pragma unroll
        for (int dhb = 0; dhb < 4; ++dhb) accv[dhb][r] *= sc;
        pv[0][r] = p0; pv[1][r] = p1; pv[2][r] = p2; pv[3][r] = p3;
      }

      char* P0 = Pt0 + wave * 2048;
      char* P1 = Pt1 + wave * 2048;
#pragma unroll
      for (int kb = 0; kb < 4; ++kb) {
#pragma unroll
        for (int r = 0; r < 4; ++r) {
          int prow = g * 4 + r;
          int key = kb * 16 + l15;
          int off = (prow * 128 + key * 2) ^ ((prow & 7) << 4);
          unsigned short h, m; split2(pv[kb][r], h, m);
          *(unsigned short*)(P0 + off) = h;
          *(unsigned short*)(P1 + off) = m;
        }
      }
      short8 pa0[2], pa1[2];
#pragma unroll
      for (int c = 0; c < 2; ++c) {
        int off = (l15 * 128 + (c * 32 + g * 8) * 2) ^ ((l15 & 7) << 4);
        pa0[c] = *(const short8*)(P0 + off);
        pa1[c] = *(const short8*)(P1 + off);
      }
      __builtin_amdgcn_s_setprio(1);
#pragma unroll
      for (int dhb = 0; dhb < 4; ++dhb) {
#pragma unroll
        for (int c = 0; c < 2; ++c) {
          int dh = dhb * 16 + l15;
          int off = (dh * 128 + (c * 32 + g * 8) * 2) ^ ((dh & 7) << 4);
          short8 bv0 = *(const short8*)((const char*)Vt0 + off);
          short8 bv1 = *(const short8*)((const char*)Vt1 + off);
          f32x4 t = accv[dhb];
          t = mfma_bf16(pa0[c], bv0, t);
          t = mfma_bf16(pa0[c], bv1, t);
          t = mfma_bf16(pa1[c], bv0, t);
          accv[dhb] = t;
        }
      }
      __builtin_amdgcn_s_setprio(0);
    }

#pragma unroll
    for (int dhb = 0; dhb < 4; ++dhb) {
#pragma unroll
      for (int r = 0; r < 4; ++r) {
        int srow2 = qlo + g * 4 + r;
        int col = hh * 64 + dhb * 16 + l15;
        unsigned short h, m; split2(accv[dhb][r] / l_[r], h, m);
        size_t idx = ((size_t)(b * TS + srow2)) * TD + col;
        A0[idx] = h; A1[idx] = m;
      }
    }
  }
}

// ---------------- MoE token pre-gather: h2p[slot] = h2[tperm[slot]] (always 2*TT slots)
__global__ __launch_bounds__(256)
void moe_gather_kernel(const unsigned short* __restrict__ h2,
                       const int* __restrict__ tperm,
                       unsigned short* __restrict__ h2p) {
  int slot = blockIdx.x;
  int t = tperm[slot];
  const ushort4v* src = (const ushort4v*)(h2 + (size_t)t * TD);
  ushort4v* dst = (ushort4v*)(h2p + (size_t)slot * TD);
  dst[threadIdx.x] = src[threadIdx.x];
}

// ---------------- MoE GEMM (plain bf16), gload_lds + dbuf + SINGLE-barrier pipeline.
// A is packed by slot (contiguous rows) for BOTH modes.
// MODE 2: up-proj, gelu -> he bf16. (Kd == Kstride, koff = 0)
// MODE 3: down-proj SPLIT-K: blockIdx.z = e*2 + ks; each half-K writes bf16
//         gated partials to ysb[ks][slot][n] (no atomics).
template<int MODE>
__global__ __launch_bounds__(256)
void gemm_bt(const unsigned short* __restrict__ A,
             const unsigned short* __restrict__ Bt,
             const float* __restrict__ bias,
             int N, int Kd, int Kstride,
             unsigned short* __restrict__ ysb,
             unsigned short* __restrict__ outH,
             const int* __restrict__ seg_off,
             const int* __restrict__ seg_cnt,
             const float* __restrict__ gate_perm) {
  __shared__ __align__(16) unsigned short As[2][4096];   // [128][32] swizzled
  __shared__ __align__(16) unsigned short Bs[2][4096];

  const int tid = threadIdx.x;
  const int lane = tid & 63;
  const int w = tid >> 6;
  const int wr = w >> 1, wc = w & 1;
  const int g = lane >> 4;
  const int l15 = lane & 15;

  const int e  = (MODE == 3) ? ((int)blockIdx.z >> 1) : (int)blockIdx.z;
  const int ks = (MODE == 3) ? ((int)blockIdx.z & 1) : 0;
  const int koff = ks * Kd;
  const int m0 = blockIdx.y * 128;
  const int n0 = blockIdx.x * 128;
  const int off = seg_off[e];
  const int Mrows = seg_cnt[e];
  if (m0 >= Mrows) return;
  Bt += (size_t)e * N * Kstride;
  bias += (size_t)e * N;

  const int c_swz = (lane & 3) ^ ((lane >> 3) & 3);
  const unsigned short* aptr[2];
  const unsigned short* bptr[2];
  int ldsrow[2];
#pragma unroll
  for (int j = 0; j < 2; ++j) {
    int r16 = w * 2 + j;
    int r = r16 * 16 + (lane >> 2);
    int rc = (m0 + r < Mrows) ? (m0 + r) : (Mrows - 1);
    aptr[j] = A + (size_t)(off + rc) * Kstride + koff + c_swz * 8;
    bptr[j] = Bt + (size_t)(n0 + r) * Kstride + koff + c_swz * 8;
    ldsrow[j] = r16 * 512;
  }

#define GB_STAGE(p, ko)                             \
  {                                                 \
    _Pragma("unroll")                               \
    for (int j = 0; j < 2; ++j) {                   \
      gload16(aptr[j] + (ko), &As[p][ldsrow[j]]);   \
      gload16(bptr[j] + (ko), &Bs[p][ldsrow[j]]);   \
    }                                               \
  }

  f32x4 acc[4][4] = {};
  const int nt = Kd >> 5;

  GB_STAGE(0, 0);
  asm volatile("s_waitcnt vmcnt(0)" ::: "memory");
  __builtin_amdgcn_s_barrier();
  for (int t = 0; t < nt; ++t) {
    const int p = t & 1;
    if (t + 1 < nt) GB_STAGE(p ^ 1, (t + 1) * 32);

    short8 af[4], bfr[4];
#pragma unroll
    for (int mi = 0; mi < 4; ++mi) {
      int row = wr * 64 + mi * 16 + l15;
      int o2 = (row * 64 + g * 16) ^ (((row >> 1) & 3) << 4);
      af[mi] = *(const short8*)((const char*)As[p] + o2);
    }
#pragma unroll
    for (int ni = 0; ni < 4; ++ni) {
      int row = wc * 64 + ni * 16 + l15;
      int o2 = (row * 64 + g * 16) ^ (((row >> 1) & 3) << 4);
      bfr[ni] = *(const short8*)((const char*)Bs[p] + o2);
    }
#pragma unroll
    for (int mi = 0; mi < 4; ++mi)
#pragma unroll
      for (int ni = 0; ni < 4; ++ni)
        acc[mi][ni] = mfma_bf16(af[mi], bfr[ni], acc[mi][ni]);
    // drain next tile's loads (issued at loop top, hidden under compute), one barrier
    asm volatile("s_waitcnt vmcnt(0)" ::: "memory");
    __builtin_amdgcn_s_barrier();
  }
#undef GB_STAGE

#pragma unroll
  for (int mi = 0; mi < 4; ++mi) {
#pragma unroll
    for (int ni = 0; ni < 4; ++ni) {
      int n = n0 + wc * 64 + ni * 16 + l15;
      float bv = (MODE == 3 && ks != 0) ? 0.0f : bias[n];
#pragma unroll
      for (int r = 0; r < 4; ++r) {
        int mloc = m0 + wr * 64 + mi * 16 + g * 4 + r;
        if (mloc >= Mrows) continue;
        float val = acc[mi][ni][r] + bv;
        if (MODE == 2) {
          outH[(size_t)(off + mloc) * TF + n] = f2bf(gelu_f(val));
        } else {
          float gv = gate_perm[off + mloc];
          ysb[(size_t)ks * (2ull * TT * TD) + (size_t)(off + mloc) * TD + n] =
              f2bf(gv * val);
        }
      }
    }
  }
}

// ---------------- MoE reduce: out[t] += sum of 4 bf16 partials; block 0 writes aux
__global__ __launch_bounds__(256)
void moe_reduce_kernel(const unsigned short* __restrict__ ys, const int* __restrict__ tslot,
                       float* __restrict__ out,
                       const int* __restrict__ counts, const float* __restrict__ p_sum) {
  int t = blockIdx.x;
  int d = threadIdx.x * 4;
  int s0 = tslot[t * 2], s1 = tslot[t * 2 + 1];
  const unsigned short* ys1 = ys + 2ull * TT * TD;
  ushort4v a0 = *(const ushort4v*)(ys  + (size_t)s0 * TD + d);
  ushort4v a1 = *(const ushort4v*)(ys1 + (size_t)s0 * TD + d);
  ushort4v b0 = *(const ushort4v*)(ys  + (size_t)s1 * TD + d);
  ushort4v b1 = *(const ushort4v*)(ys1 + (size_t)s1 * TD + d);
  float* o = out + (size_t)t * TD + d;
  fvec4 c = *(const fvec4*)o;
#pragma unroll
  for (int j = 0; j < 4; ++j)
    c[j] += bf2f(a0[j]) + bf2f(a1[j]) + bf2f(b0[j]) + bf2f(b1[j]);
  *(fvec4*)o = c;
  if (t == 0 && threadIdx.x == 0) {
    float a = 0.f;
    for (int e2 = 0; e2 < TE; ++e2)
      a += ((float)counts[e2] / (float)TT) * (p_sum[e2] / (float)TT);
    out[(size_t)TT * TD] = (float)TE * a;
  }
}

// ---------------- router: per-block LDS aggregation + fused h2 (bf16 rmsnorm) write
__global__ __launch_bounds__(256)
void router_kernel(const float* __restrict__ X1, const float* __restrict__ N2W,
                   const float* __restrict__ RW, const float* __restrict__ RB,
                   int* __restrict__ top_e, float* __restrict__ top_g,
                   int* __restrict__ counts, float* __restrict__ p_sum,
                   unsigned short* __restrict__ h2) {
  __shared__ float s_psum[TE];
  __shared__ int s_cnt[TE];
  if (threadIdx.x < TE) { s_psum[threadIdx.x] = 0.f; s_cnt[threadIdx.x] = 0; }
  __syncthreads();
  int lane = threadIdx.x & 63, wave = threadIdx.x >> 6;
  for (int it = 0; it < 16; ++it) {
    int t = (blockIdx.x * 4 + wave) * 16 + it;
    const float* xr = X1 + (size_t)t * TD;
    float vals[16]; float ss = 0.f;
#pragma unroll
    for (int i = 0; i < 16; ++i) { float xv = xr[i * 64 + lane]; vals[i] = xv; ss += xv * xv; }
#pragma unroll
    for (int msk = 1; msk < 64; msk <<= 1) ss += __shfl_xor(ss, msk);
    float rs = rsqrtf(ss * (1.0f / TD) + 1e-6f);
    float acc[TE] = {};
#pragma unroll
    for (int i = 0; i < 16; ++i) {
      int d = i * 64 + lane;
      float nv = vals[i] * rs * N2W[d];
      h2[(size_t)t * TD + d] = f2bf(nv);     // fused rmsnorm output (MoE expert input)
      const float* rwp = RW + (size_t)d * TE;
#pragma unroll
      for (int e2 = 0; e2 < TE; ++e2) acc[e2] += nv * rwp[e2];
    }
#pragma unroll
    for (int msk = 1; msk < 64; msk <<= 1)
#pragma unroll
      for (int e2 = 0; e2 < TE; ++e2) acc[e2] += __shfl_xor(acc[e2], msk);
    if (lane == 0) {
      float lg[TE]; float mx = -1e30f;
      for (int e2 = 0; e2 < TE; ++e2) { lg[e2] = acc[e2] + RB[e2]; mx = fmaxf(mx, lg[e2]); }
      float sum = 0.f, pe[TE];
      for (int e2 = 0; e2 < TE; ++e2) { pe[e2] = expf(lg[e2] - mx); sum += pe[e2]; }
      float inv = 1.0f / sum;
      for (int e2 = 0; e2 < TE; ++e2) atomicAdd(&s_psum[e2], pe[e2] * inv);
      int i1 = 0;
      for (int e2 = 1; e2 < TE; ++e2) if (lg[e2] > lg[i1]) i1 = e2;
      int i2 = (i1 == 0) ? 1 : 0;
      for (int e2 = 0; e2 < TE; ++e2) if (e2 != i1 && lg[e2] > lg[i2]) i2 = e2;
      float g1 = pe[i1], g2 = pe[i2], gs = g1 + g2;
      top_e[t * 2] = i1; top_e[t * 2 + 1] = i2;
      top_g[t * 2] = g1 / gs; top_g[t * 2 + 1] = g2 / gs;
      atomicAdd(&s_cnt[i1], 1); atomicAdd(&s_cnt[i2], 1);
    }
  }
  __syncthreads();
  if (threadIdx.x < TE) {
    atomicAdd(&p_sum[threadIdx.x], s_psum[threadIdx.x]);
    atomicAdd(&counts[threadIdx.x], s_cnt[threadIdx.x]);
  }
}

__global__ void zero_meta_kernel(int* counts, float* p_sum) {
  int t = threadIdx.x;
  if (t < TE) { counts[t] = 0; p_sum[t] = 0.f; }
}

__global__ void offsets_kernel(const int* counts, int* offs, int* cursor) {
  if (threadIdx.x == 0) {
    int o = 0;
    for (int e2 = 0; e2 < TE; ++e2) { offs[e2] = o; o += counts[e2]; }
  }
  if (threadIdx.x < TE) cursor[threadIdx.x] = 0;
}

// ---------------- fill: per-block LDS histogram + range-reserve; records slots
__global__ __launch_bounds__(256)
void fill_kernel(const int* __restrict__ top_e, const float* __restrict__ top_g,
                 const int* __restrict__ offs, int* __restrict__ cursor,
                 int* __restrict__ token_perm, float* __restrict__ gate_perm,
                 int* __restrict__ tslot) {
  __shared__ int s_cnt[TE], s_base[TE];
  if (threadIdx.x < TE) s_cnt[threadIdx.x] = 0;
  __syncthreads();
  int t = blockIdx.x * 256 + threadIdx.x;
  int e0 = top_e[t * 2], e1 = top_e[t * 2 + 1];
  int r0 = atomicAdd(&s_cnt[e0], 1);
  int r1 = atomicAdd(&s_cnt[e1], 1);
  __syncthreads();
  if (threadIdx.x < TE)
    s_base[threadIdx.x] = atomicAdd(&cursor[threadIdx.x], s_cnt[threadIdx.x]);
  __syncthreads();
  int p0 = offs[e0] + s_base[e0] + r0;
  int p1 = offs[e1] + s_base[e1] + r1;
  token_perm[p0] = t; gate_perm[p0] = top_g[t * 2];
  token_perm[p1] = t; gate_perm[p1] = top_g[t * 2 + 1];
  tslot[t * 2] = p0; tslot[t * 2 + 1] = p1;
}

extern "C" void kernel_launch(void* const* d_in, const int* in_sizes, int n_in,
                              void* d_out, int out_size, void* d_ws, size_t ws_size,
                              hipStream_t stream) {
  const float* x     = (const float*)d_in[0];
  const float* n1w   = (const float*)d_in[1];
  const float* n2w   = (const float*)d_in[2];
  const float* w_qkv = (const float*)d_in[3];
  const float* b_qkv = (const float*)d_in[4];
  const float* w_o   = (const float*)d_in[5];
  const float* b_o   = (const float*)d_in[6];
  const float* rw    = (const float*)d_in[7];
  const float* rb    = (const float*)d_in[8];
  const float* w1    = (const float*)d_in[9];
  const float* b1    = (const float*)d_in[10];
  const float* w2    = (const float*)d_in[11];
  const float* b2    = (const float*)d_in[12];
  float* out = (float*)d_out;
  char* ws = (char*)d_ws;

  size_t o = 0;
  auto give = [&](size_t bytes) -> char* {
    char* p = ws + o;
    o += (bytes + 255) & ~(size_t)255;
    return p;
  };
  unsigned short* w1T = (unsigned short*)give(8ull * 4096 * 1024 * 2);   // 64MB
  unsigned short* w2T = (unsigned short*)give(8ull * 1024 * 4096 * 2);   // 64MB
  unsigned short* wo0 = (unsigned short*)give(1024ull * 1024 * 2);
  unsigned short* wo1 = (unsigned short*)give(1024ull * 1024 * 2);
  unsigned short* h2  = (unsigned short*)give((size_t)TT * TD * 2);      // 8MB
  int*   counts = (int*)give(TE * 4);
  int*   cursor = (int*)give(TE * 4);
  int*   offs   = (int*)give(TE * 4);
  float* psum   = (float*)give(TE * 4);
  int*   top_e  = (int*)give(2ull * TT * 4);
  float* top_g  = (float*)give(2ull * TT * 4);
  int*   tperm  = (int*)give(2ull * TT * 4);
  float* gperm  = (float*)give(2ull * TT * 4);
  int*   tslot  = (int*)give(2ull * TT * 4);
  unsigned short* wq0 = (unsigned short*)give(3072ull * 1024 * 2);
  unsigned short* wq1 = (unsigned short*)give(3072ull * 1024 * 2);
  unsigned short* ysb = (unsigned short*)give(2ull * 2 * TT * TD * 2);   // 32MB (2 K-halves, bf16)
  // pool B: h1 pair (dead after gemm2<0>) aliased with ao pair (dead after gemm2<1>)
  // then reused as h2p packed MoE input (born after fill)
  char* poolB = give(2ull * TT * TD * 2);                                // 16MB
  unsigned short* h10 = (unsigned short*)poolB;
  unsigned short* h11 = (unsigned short*)(poolB + (size_t)TT * TD * 2);
  unsigned short* ao0 = h10; unsigned short* ao1 = h11;
  unsigned short* h2p = (unsigned short*)poolB;                          // [2TT][TD] bf16
  // pool C: qkv split pair (dead after attn) aliased with he (born at MoE up)
  char* poolC = give(64ull * 1024 * 1024);                               // 64MB
  unsigned short* qs0 = (unsigned short*)poolC;
  unsigned short* qs1 = (unsigned short*)(poolC + 3ull * PSTR * 2);
  unsigned short* he  = (unsigned short*)poolC;                          // [2TT][TF] bf16

  // weight prep
  tcvt_split_kernel<<<dim3(96, 32, 1), 256, 0, stream>>>(w_qkv, wq0, wq1, 1024, 3072);
  tcvt_split_kernel<<<dim3(32, 32, 1), 256, 0, stream>>>(w_o, wo0, wo1, 1024, 1024);
  tcvt_kernel<<<dim3(128, 32, 8), 256, 0, stream>>>(w1, w1T, 1024, 4096);
  tcvt_kernel<<<dim3(32, 128, 8), 256, 0, stream>>>(w2, w2T, 4096, 1024);

  // attention path (2-way split, 3-product; all operands pre-split)
  rmsnorm_split_kernel<<<dim3(TT), 256, 0, stream>>>(x, n1w, h10, h11);
  gemm2<0><<<dim3(24, 32, 1), 256, 0, stream>>>(
      h10, h11, wq0, wq1, b_qkv, 1024, nullptr, nullptr, qs0, qs1);
  attn2_kernel<<<dim3(8, 32, 1), 512, 0, stream>>>(qs0, qs1, ao0, ao1);
  gemm2<1><<<dim3(8, 32, 1), 256, 0, stream>>>(
      ao0, ao1, wo0, wo1, b_o, 1024, out, x, nullptr, nullptr);

  // MoE path (bf16); router fuses the rmsnorm h2 write
  zero_meta_kernel<<<dim3(1), 64, 0, stream>>>(counts, psum);
  router_kernel<<<dim3(64), 256, 0, stream>>>(out, n2w, rw, rb, top_e, top_g, counts, psum, h2);
  offsets_kernel<<<dim3(1), 64, 0, stream>>>(counts, offs, cursor);
  fill_kernel<<<dim3(TT / 256), 256, 0, stream>>>(top_e, top_g, offs, cursor, tperm, gperm, tslot);
  moe_gather_kernel<<<dim3(2 * TT), 256, 0, stream>>>(h2, tperm, h2p);
  gemm_bt<2><<<dim3(32, 32, 8), 256, 0, stream>>>(
      h2p, w1T, b1, 4096, 1024, 1024, nullptr, he, offs, counts, gperm);
  gemm_bt<3><<<dim3(8, 32, 16), 256, 0, stream>>>(
      he, w2T, b2, 1024, 2048, 4096, ysb, nullptr, offs, counts, gperm);
  moe_reduce_kernel<<<dim3(TT), 256, 0, stream>>>(ysb, tslot, out, counts, psum);
}

// Round 17
// 727.579 us; speedup vs baseline: 1.0649x; 1.0079x over previous
//
#include <hip/hip_runtime.h>
#include <math.h>

#define TB 2
#define TS 2048
#define TD 1024
#define TH 16
#define TDH 64
#define TF 4096
#define TE 8
#define TT 4096                 // B*S tokens
#define PSTR (TB*TH*TS*TDH)     // 4194304 elements per q/k/v part

typedef __attribute__((ext_vector_type(8))) __bf16 bf16x8;
typedef __attribute__((ext_vector_type(4))) float f32x4;
typedef __attribute__((ext_vector_type(8))) short short8;
typedef __attribute__((ext_vector_type(4))) unsigned short ushort4v;
typedef __attribute__((ext_vector_type(4))) float fvec4;

__device__ inline unsigned short f2bf(float f) {
  union { float f; unsigned int u; } v; v.f = f;
  unsigned int u = v.u;
  unsigned int r = (u + 0x7FFFu + ((u >> 16) & 1u)) >> 16;
  return (unsigned short)r;
}
__device__ inline float bf2f(unsigned short h) {
  union { unsigned int u; float f; } v; v.u = ((unsigned int)h) << 16; return v.f;
}
// 2-way bf16 split: h+m reproduces ~17 mantissa bits (residual ~2^-18)
__device__ inline void split2(float x, unsigned short& h, unsigned short& m) {
  h = f2bf(x);
  m = f2bf(x - bf2f(h));
}

__device__ inline f32x4 mfma_bf16(short8 a, short8 b, f32x4 c) {
  return __builtin_amdgcn_mfma_f32_16x16x32_bf16(
      __builtin_bit_cast(bf16x8, a), __builtin_bit_cast(bf16x8, b), c, 0, 0, 0);
}

// async global->LDS, 16B per lane. LDS dest = wave-uniform base + lane*16.
__device__ inline void gload16(const void* g, void* l) {
  __builtin_amdgcn_global_load_lds(
      (const __attribute__((address_space(1))) void*)g,
      (__attribute__((address_space(3))) void*)l, 16, 0, 0);
}

// fast exact-GELU: erf via Abramowitz-Stegun 7.1.26 (|abs err| < 1.5e-7)
__device__ inline float gelu_f(float v) {
  float ax = fabsf(v) * 0.70710678118654752f;
  float t = __builtin_amdgcn_rcpf(1.0f + 0.3275911f * ax);
  float poly = ((((1.061405429f * t - 1.453152027f) * t + 1.421413741f) * t
                 - 0.284496736f) * t + 0.254829592f) * t;
  float er = 1.0f - poly * __expf(-ax * ax);
  er = copysignf(er, v);
  return 0.5f * v * (1.0f + er);
}

// ---------------- transpose + f32->bf16 convert: in [R,C] f32 -> out [C,R] bf16
// 64x64 tiles: 256B-contiguous loads, 128B-contiguous bf16 stores.
__global__ __launch_bounds__(256)
void tcvt_kernel(const float* __restrict__ In, unsigned short* __restrict__ Out,
                 int R, int C) {
  __shared__ float tile[64][65];
  In  += (size_t)blockIdx.z * R * C;
  Out += (size_t)blockIdx.z * R * C;
  int c0 = blockIdx.x * 64, r0 = blockIdx.y * 64;
  int tx = threadIdx.x & 63, ty = threadIdx.x >> 6;  // ty 0..3
#pragma unroll
  for (int i = 0; i < 16; ++i) {
    int row = ty + 4 * i;
    tile[row][tx] = In[(size_t)(r0 + row) * C + c0 + tx];
  }
  __syncthreads();
#pragma unroll
  for (int i = 0; i < 16; ++i) {
    int orow = ty + 4 * i;
    Out[(size_t)(c0 + orow) * R + r0 + tx] = f2bf(tile[tx][orow]);
  }
}

// ---------------- transpose + 2-way split: in [R,C] f32 -> 2x [C,R] bf16 (64x64)
__global__ __launch_bounds__(256)
void tcvt_split_kernel(const float* __restrict__ In,
                       unsigned short* __restrict__ O0,
                       unsigned short* __restrict__ O1, int R, int C) {
  __shared__ float tile[64][65];
  int c0 = blockIdx.x * 64, r0 = blockIdx.y * 64;
  int tx = threadIdx.x & 63, ty = threadIdx.x >> 6;
#pragma unroll
  for (int i = 0; i < 16; ++i) {
    int row = ty + 4 * i;
    tile[row][tx] = In[(size_t)(r0 + row) * C + c0 + tx];
  }
  __syncthreads();
#pragma unroll
  for (int i = 0; i < 16; ++i) {
    int orow = ty + 4 * i;
    float v = tile[tx][orow];
    unsigned short h, m; split2(v, h, m);
    size_t idx = (size_t)(c0 + orow) * R + r0 + tx;
    O0[idx] = h; O1[idx] = m;
  }
}

// ---------------- RMSNorm f32 in -> pre-split bf16 pair (attention input h1)
__global__ __launch_bounds__(256)
void rmsnorm_split_kernel(const float* __restrict__ X, const float* __restrict__ W,
                          unsigned short* __restrict__ O0,
                          unsigned short* __restrict__ O1) {
  int row = blockIdx.x;
  int tid = threadIdx.x;
  int lane = tid & 63, wave = tid >> 6;
  const float* xr = X + (size_t)row * TD;
  fvec4 v = *(const fvec4*)(xr + tid * 4);
  float ss = v[0]*v[0] + v[1]*v[1] + v[2]*v[2] + v[3]*v[3];
#pragma unroll
  for (int msk = 1; msk < 64; msk <<= 1) ss += __shfl_xor(ss, msk);
  __shared__ float red[4];
  if (lane == 0) red[wave] = ss;
  __syncthreads();
  ss = red[0] + red[1] + red[2] + red[3];
  float rs = rsqrtf(ss * (1.0f / TD) + 1e-6f);
  fvec4 wv = *(const fvec4*)(W + tid * 4);
  ushort4v o0, o1;
#pragma unroll
  for (int j = 0; j < 4; ++j) {
    unsigned short h, m; split2(v[j] * rs * wv[j], h, m);
    o0[j] = h; o1[j] = m;
  }
  size_t idx = (size_t)row * TD + tid * 4;
  *(ushort4v*)(O0 + idx) = o0;
  *(ushort4v*)(O1 + idx) = o1;
}

// ---------------- high-precision GEMM: A,B pre-split bf16 pairs, 3-product split.
// gload_lds staging, dbuf, SINGLE-barrier pipeline (stage-top, drain-after-compute).
// MODE 0: QKV -> scatter pairs: Q,K at [bh][s][dh]; V transposed [bh][dh][s]
// MODE 1: f32 out = acc + bias + resid
template<int MODE>
__global__ __launch_bounds__(256)
void gemm2(const unsigned short* __restrict__ A0,
           const unsigned short* __restrict__ A1,
           const unsigned short* __restrict__ B0,
           const unsigned short* __restrict__ B1,
           const float* __restrict__ bias, int Kd,
           float* __restrict__ outF, const float* __restrict__ resid,
           unsigned short* __restrict__ S0,
           unsigned short* __restrict__ S1) {
  __shared__ __align__(16) unsigned short As0[2][4096], As1[2][4096];
  __shared__ __align__(16) unsigned short Bs0[2][4096], Bs1[2][4096];
  const int tid = threadIdx.x;
  const int lane = tid & 63;
  const int w = tid >> 6;
  const int wr = w >> 1, wc = w & 1;
  const int g = lane >> 4;
  const int l15 = lane & 15;
  const int m0 = blockIdx.y * 128;
  const int n0 = blockIdx.x * 128;

  const int c_swz = (lane & 3) ^ ((lane >> 3) & 3);
  const unsigned short *a0p[2], *a1p[2], *b0p[2], *b1p[2];
  int ldsrow[2];
#pragma unroll
  for (int j = 0; j < 2; ++j) {
    int r16 = w * 2 + j;
    int r = r16 * 16 + (lane >> 2);
    a0p[j] = A0 + (size_t)(m0 + r) * Kd + c_swz * 8;
    a1p[j] = A1 + (size_t)(m0 + r) * Kd + c_swz * 8;
    b0p[j] = B0 + (size_t)(n0 + r) * Kd + c_swz * 8;
    b1p[j] = B1 + (size_t)(n0 + r) * Kd + c_swz * 8;
    ldsrow[j] = r16 * 512;
  }

#define G2_STAGE(p, koff)                              \
  {                                                    \
    _Pragma("unroll")                                  \
    for (int j = 0; j < 2; ++j) {                      \
      gload16(a0p[j] + (koff), &As0[p][ldsrow[j]]);    \
      gload16(a1p[j] + (koff), &As1[p][ldsrow[j]]);    \
      gload16(b0p[j] + (koff), &Bs0[p][ldsrow[j]]);    \
      gload16(b1p[j] + (koff), &Bs1[p][ldsrow[j]]);    \
    }                                                  \
  }

  f32x4 acc[4][4] = {};
  const int nt = Kd >> 5;

  G2_STAGE(0, 0);
  asm volatile("s_waitcnt vmcnt(0)" ::: "memory");
  __builtin_amdgcn_s_barrier();
  for (int t = 0; t < nt; ++t) {
    const int p = t & 1;
    if (t + 1 < nt) G2_STAGE(p ^ 1, (t + 1) * 32);

    short8 a0f[4], a1f[4], b0f[4], b1f[4];
#pragma unroll
    for (int mi = 0; mi < 4; ++mi) {
      int row = wr * 64 + mi * 16 + l15;
      int off = (row * 64 + g * 16) ^ (((row >> 1) & 3) << 4);
      a0f[mi] = *(const short8*)((const char*)As0[p] + off);
      a1f[mi] = *(const short8*)((const char*)As1[p] + off);
    }
#pragma unroll
    for (int ni = 0; ni < 4; ++ni) {
      int row = wc * 64 + ni * 16 + l15;
      int off = (row * 64 + g * 16) ^ (((row >> 1) & 3) << 4);
      b0f[ni] = *(const short8*)((const char*)Bs0[p] + off);
      b1f[ni] = *(const short8*)((const char*)Bs1[p] + off);
    }
#pragma unroll
    for (int mi = 0; mi < 4; ++mi)
#pragma unroll
      for (int ni = 0; ni < 4; ++ni) {
        f32x4 tacc = acc[mi][ni];
        tacc = mfma_bf16(a0f[mi], b0f[ni], tacc);
        tacc = mfma_bf16(a0f[mi], b1f[ni], tacc);
        tacc = mfma_bf16(a1f[mi], b0f[ni], tacc);
        acc[mi][ni] = tacc;
      }
    // drain next tile's loads (issued at loop top, hidden under compute), one barrier
    asm volatile("s_waitcnt vmcnt(0)" ::: "memory");
    __builtin_amdgcn_s_barrier();
  }
#undef G2_STAGE

#pragma unroll
  for (int mi = 0; mi < 4; ++mi) {
#pragma unroll
    for (int ni = 0; ni < 4; ++ni) {
      int n = n0 + wc * 64 + ni * 16 + l15;
      float bv = bias[n];
      if (MODE == 0) {
        int part = n >> 10, d = n & 1023, hh = d >> 6, dh = d & 63;
        int s0r = m0 + wr * 64 + mi * 16 + g * 4;
        int b = s0r >> 11, s_ = s0r & 2047;
        int bh = b * TH + hh;
        if (part < 2) {
          size_t base = (size_t)part * PSTR + (size_t)bh * (TS * TDH) + (size_t)s_ * TDH + dh;
#pragma unroll
          for (int r = 0; r < 4; ++r) {
            unsigned short h, m; split2(acc[mi][ni][r] + bv, h, m);
            size_t idx = base + (size_t)r * TDH;
            S0[idx] = h; S1[idx] = m;
          }
        } else {
          ushort4v o0, o1;
#pragma unroll
          for (int r = 0; r < 4; ++r) {
            unsigned short h, m; split2(acc[mi][ni][r] + bv, h, m);
            o0[r] = h; o1[r] = m;
          }
          size_t idx = 2 * (size_t)PSTR + (size_t)bh * (TS * TDH) + (size_t)dh * TS + s_;
          *(ushort4v*)(S0 + idx) = o0;
          *(ushort4v*)(S1 + idx) = o1;
        }
      } else {
#pragma unroll
        for (int r = 0; r < 4; ++r) {
          int m = m0 + wr * 64 + mi * 16 + g * 4 + r;
          size_t idx = (size_t)m * TD + n;
          outF[idx] = acc[mi][ni][r] + bv + resid[idx];
        }
      }
    }
  }
}

// ---------------- flash attention, causal, 3-product split, pre-split bf16 I/O
// 8 waves / 512 threads; block handles q-tiles bx and 15-bx (heavy+light fused).
// K/V staged via global_load_lds with pre-swizzled source (linear LDS dest).
__global__ __launch_bounds__(512, 4)
void attn2_kernel(const unsigned short* __restrict__ S0,
                  const unsigned short* __restrict__ S1,
                  unsigned short* __restrict__ A0,
                  unsigned short* __restrict__ A1) {
  __shared__ __align__(16) unsigned short Kt0[4096], Kt1[4096];
  __shared__ __align__(16) unsigned short Vt0[4096], Vt1[4096];
  __shared__ __align__(16) char Pt0[16384], Pt1[16384];

  const int tid = threadIdx.x;
  const int lane = tid & 63;
  const int wave = tid >> 6;          // 0..7
  const int g = lane >> 4, l15 = lane & 15;

  const int bh = blockIdx.y;
  const int b = bh >> 4, hh = bh & 15;

  const size_t qbase = (size_t)bh * TS * TDH;
  const size_t kbase = (size_t)PSTR + qbase;
  const size_t vbase = 2 * (size_t)PSTR + qbase;   // [dh][s] layout

  const int srow = wave * 8 + (lane >> 3);
  const int scw = (lane & 7) ^ (srow & 7);
  unsigned short* const kdst0 = Kt0 + wave * 512;   // 8 rows * 64 elems
  unsigned short* const kdst1 = Kt1 + wave * 512;
  unsigned short* const vdst0 = Vt0 + wave * 512;
  unsigned short* const vdst1 = Vt1 + wave * 512;

  for (int half = 0; half < 2; ++half) {
    const int qtb = half ? (15 - (int)blockIdx.x) : (int)blockIdx.x;
    const int qlo = qtb * 128 + wave * 16;         // wave's first q row

    short8 aq0[2], aq1[2];
#pragma unroll
    for (int c = 0; c < 2; ++c) {
      size_t qo = qbase + (size_t)(qlo + l15) * TDH + c * 32 + g * 8;
      aq0[c] = *(const short8*)(S0 + qo);
      aq1[c] = *(const short8*)(S1 + qo);
    }

    f32x4 accv[4] = {};
    float m_[4] = {-1e30f, -1e30f, -1e30f, -1e30f};
    float l_[4] = {0.f, 0.f, 0.f, 0.f};

    const int ktmax = 2 * qtb + 1;
    for (int kt = 0; kt <= ktmax; ++kt) {
      __syncthreads();   // prior compute done reading LDS
      {
        size_t kg = kbase + (size_t)(kt * 64 + srow) * TDH + scw * 8;
        gload16(S0 + kg, kdst0);
        gload16(S1 + kg, kdst1);
        size_t vg = vbase + (size_t)srow * TS + kt * 64 + scw * 8;
        gload16(S0 + vg, vdst0);
        gload16(S1 + vg, vdst1);
      }
      __syncthreads();   // drains vmcnt(0): tile resident

      if (kt * 64 > qlo + 15) continue;   // above diagonal for this wave
      const bool needmask = (kt * 64 + 63 > qlo);

      f32x4 sf[4] = {};
      __builtin_amdgcn_s_setprio(1);
#pragma unroll
      for (int kb = 0; kb < 4; ++kb) {
#pragma unroll
        for (int c = 0; c < 2; ++c) {
          int krow = kb * 16 + l15;
          int off = (krow * 128 + (c * 32 + g * 8) * 2) ^ ((krow & 7) << 4);
          short8 bk0 = *(const short8*)((const char*)Kt0 + off);
          short8 bk1 = *(const short8*)((const char*)Kt1 + off);
          f32x4 t = sf[kb];
          t = mfma_bf16(aq0[c], bk0, t);
          t = mfma_bf16(aq0[c], bk1, t);
          t = mfma_bf16(aq1[c], bk0, t);
          sf[kb] = t;
        }
      }
      __builtin_amdgcn_s_setprio(0);

      float pv[4][4];
#pragma unroll
      for (int r = 0; r < 4; ++r) {
        float s0 = sf[0][r] * 0.125f, s1 = sf[1][r] * 0.125f;
        float s2 = sf[2][r] * 0.125f, s3 = sf[3][r] * 0.125f;
        if (needmask) {
          int qg = qlo + g * 4 + r;
          int k0g = kt * 64 + l15;
          if (k0g      > qg) s0 = -1e30f;
          if (k0g + 16 > qg) s1 = -1e30f;
          if (k0g + 32 > qg) s2 = -1e30f;
          if (k0g + 48 > qg) s3 = -1e30f;
        }
        float mx = fmaxf(fmaxf(s0, s1), fmaxf(s2, s3));
#pragma unroll
        for (int msk = 1; msk < 16; msk <<= 1) mx = fmaxf(mx, __shfl_xor(mx, msk));
        float nm = fmaxf(m_[r], mx);
        float sc = __expf(m_[r] - nm);
        float p0 = __expf(s0 - nm), p1 = __expf(s1 - nm);
        float p2 = __expf(s2 - nm), p3 = __expf(s3 - nm);
        float rs = p0 + p1 + p2 + p3;
#pragma unroll
        for (int msk = 1; msk < 16; msk <<= 1) rs += __shfl_xor(rs, msk);
        m_[r] = nm;
        l_[r] = l_[r] * sc + rs;
#pragma unroll
        for (int dhb = 0; dhb < 4; ++dhb) accv[dhb][r] *= sc;
        pv[0][r] = p0; pv[1][r] = p1; pv[2][r] = p2; pv[3][r] = p3;
      }

      char* P0 = Pt0 + wave * 2048;
      char* P1 = Pt1 + wave * 2048;
#pragma unroll
      for (int kb = 0; kb < 4; ++kb) {
#pragma unroll
        for (int r = 0; r < 4; ++r) {
          int prow = g * 4 + r;
          int key = kb * 16 + l15;
          int off = (prow * 128 + key * 2) ^ ((prow & 7) << 4);
          unsigned short h, m; split2(pv[kb][r], h, m);
          *(unsigned short*)(P0 + off) = h;
          *(unsigned short*)(P1 + off) = m;
        }
      }
      short8 pa0[2], pa1[2];
#pragma unroll
      for (int c = 0; c < 2; ++c) {
        int off = (l15 * 128 + (c * 32 + g * 8) * 2) ^ ((l15 & 7) << 4);
        pa0[c] = *(const short8*)(P0 + off);
        pa1[c] = *(const short8*)(P1 + off);
      }
      __builtin_amdgcn_s_setprio(1);
#pragma unroll
      for (int dhb = 0; dhb < 4; ++dhb) {
#pragma unroll
        for (int c = 0; c < 2; ++c) {
          int dh = dhb * 16 + l15;
          int off = (dh * 128 + (c * 32 + g * 8) * 2) ^ ((dh & 7) << 4);
          short8 bv0 = *(const short8*)((const char*)Vt0 + off);
          short8 bv1 = *(const short8*)((const char*)Vt1 + off);
          f32x4 t = accv[dhb];
          t = mfma_bf16(pa0[c], bv0, t);
          t = mfma_bf16(pa0[c], bv1, t);
          t = mfma_bf16(pa1[c], bv0, t);
          accv[dhb] = t;
        }
      }
      __builtin_amdgcn_s_setprio(0);
    }

#pragma unroll
    for (int dhb = 0; dhb < 4; ++dhb) {
#pragma unroll
      for (int r = 0; r < 4; ++r) {
        int srow2 = qlo + g * 4 + r;
        int col = hh * 64 + dhb * 16 + l15;
        unsigned short h, m; split2(accv[dhb][r] / l_[r], h, m);
        size_t idx = ((size_t)(b * TS + srow2)) * TD + col;
        A0[idx] = h; A1[idx] = m;
      }
    }
  }
}

// ---------------- MoE token pre-gather: h2p[slot] = h2[tperm[slot]] (always 2*TT slots)
__global__ __launch_bounds__(256)
void moe_gather_kernel(const unsigned short* __restrict__ h2,
                       const int* __restrict__ tperm,
                       unsigned short* __restrict__ h2p) {
  int slot = blockIdx.x;
  int t = tperm[slot];
  const ushort4v* src = (const ushort4v*)(h2 + (size_t)t * TD);
  ushort4v* dst = (ushort4v*)(h2p + (size_t)slot * TD);
  dst[threadIdx.x] = src[threadIdx.x];
}

// ---------------- MoE GEMM (plain bf16), gload_lds + dbuf + SINGLE-barrier pipeline.
// A is packed by slot (contiguous rows) for BOTH modes.
// MODE 2: up-proj, gelu -> he bf16. (Kd == Kstride, koff = 0)
// MODE 3: down-proj SPLIT-K: blockIdx.z = e*2 + ks; each half-K writes bf16
//         gated partials to ysb[ks][slot][n] (no atomics).
template<int MODE>
__global__ __launch_bounds__(256)
void gemm_bt(const unsigned short* __restrict__ A,
             const unsigned short* __restrict__ Bt,
             const float* __restrict__ bias,
             int N, int Kd, int Kstride,
             unsigned short* __restrict__ ysb,
             unsigned short* __restrict__ outH,
             const int* __restrict__ seg_off,
             const int* __restrict__ seg_cnt,
             const float* __restrict__ gate_perm) {
  __shared__ __align__(16) unsigned short As[2][4096];   // [128][32] swizzled
  __shared__ __align__(16) unsigned short Bs[2][4096];

  const int tid = threadIdx.x;
  const int lane = tid & 63;
  const int w = tid >> 6;
  const int wr = w >> 1, wc = w & 1;
  const int g = lane >> 4;
  const int l15 = lane & 15;

  const int e  = (MODE == 3) ? ((int)blockIdx.z >> 1) : (int)blockIdx.z;
  const int ks = (MODE == 3) ? ((int)blockIdx.z & 1) : 0;
  const int koff = ks * Kd;
  const int m0 = blockIdx.y * 128;
  const int n0 = blockIdx.x * 128;
  const int off = seg_off[e];
  const int Mrows = seg_cnt[e];
  if (m0 >= Mrows) return;
  Bt += (size_t)e * N * Kstride;
  bias += (size_t)e * N;

  const int c_swz = (lane & 3) ^ ((lane >> 3) & 3);
  const unsigned short* aptr[2];
  const unsigned short* bptr[2];
  int ldsrow[2];
#pragma unroll
  for (int j = 0; j < 2; ++j) {
    int r16 = w * 2 + j;
    int r = r16 * 16 + (lane >> 2);
    int rc = (m0 + r < Mrows) ? (m0 + r) : (Mrows - 1);
    aptr[j] = A + (size_t)(off + rc) * Kstride + koff + c_swz * 8;
    bptr[j] = Bt + (size_t)(n0 + r) * Kstride + koff + c_swz * 8;
    ldsrow[j] = r16 * 512;
  }

#define GB_STAGE(p, ko)                             \
  {                                                 \
    _Pragma("unroll")                               \
    for (int j = 0; j < 2; ++j) {                   \
      gload16(aptr[j] + (ko), &As[p][ldsrow[j]]);   \
      gload16(bptr[j] + (ko), &Bs[p][ldsrow[j]]);   \
    }                                               \
  }

  f32x4 acc[4][4] = {};
  const int nt = Kd >> 5;

  GB_STAGE(0, 0);
  asm volatile("s_waitcnt vmcnt(0)" ::: "memory");
  __builtin_amdgcn_s_barrier();
  for (int t = 0; t < nt; ++t) {
    const int p = t & 1;
    if (t + 1 < nt) GB_STAGE(p ^ 1, (t + 1) * 32);

    short8 af[4], bfr[4];
#pragma unroll
    for (int mi = 0; mi < 4; ++mi) {
      int row = wr * 64 + mi * 16 + l15;
      int o2 = (row * 64 + g * 16) ^ (((row >> 1) & 3) << 4);
      af[mi] = *(const short8*)((const char*)As[p] + o2);
    }
#pragma unroll
    for (int ni = 0; ni < 4; ++ni) {
      int row = wc * 64 + ni * 16 + l15;
      int o2 = (row * 64 + g * 16) ^ (((row >> 1) & 3) << 4);
      bfr[ni] = *(const short8*)((const char*)Bs[p] + o2);
    }
#pragma unroll
    for (int mi = 0; mi < 4; ++mi)
#pragma unroll
      for (int ni = 0; ni < 4; ++ni)
        acc[mi][ni] = mfma_bf16(af[mi], bfr[ni], acc[mi][ni]);
    // drain next tile's loads (issued at loop top, hidden under compute), one barrier
    asm volatile("s_waitcnt vmcnt(0)" ::: "memory");
    __builtin_amdgcn_s_barrier();
  }
#undef GB_STAGE

#pragma unroll
  for (int mi = 0; mi < 4; ++mi) {
#pragma unroll
    for (int ni = 0; ni < 4; ++ni) {
      int n = n0 + wc * 64 + ni * 16 + l15;
      float bv = (MODE == 3 && ks != 0) ? 0.0f : bias[n];
#pragma unroll
      for (int r = 0; r < 4; ++r) {
        int mloc = m0 + wr * 64 + mi * 16 + g * 4 + r;
        if (mloc >= Mrows) continue;
        float val = acc[mi][ni][r] + bv;
        if (MODE == 2) {
          outH[(size_t)(off + mloc) * TF + n] = f2bf(gelu_f(val));
        } else {
          float gv = gate_perm[off + mloc];
          ysb[(size_t)ks * (2ull * TT * TD) + (size_t)(off + mloc) * TD + n] =
              f2bf(gv * val);
        }
      }
    }
  }
}

// ---------------- MoE reduce: out[t] += sum of 4 bf16 partials; block 0 writes aux
__global__ __launch_bounds__(256)
void moe_reduce_kernel(const unsigned short* __restrict__ ys, const int* __restrict__ tslot,
                       float* __restrict__ out,
                       const int* __restrict__ counts, const float* __restrict__ p_sum) {
  int t = blockIdx.x;
  int d = threadIdx.x * 4;
  int s0 = tslot[t * 2], s1 = tslot[t * 2 + 1];
  const unsigned short* ys1 = ys + 2ull * TT * TD;
  ushort4v a0 = *(const ushort4v*)(ys  + (size_t)s0 * TD + d);
  ushort4v a1 = *(const ushort4v*)(ys1 + (size_t)s0 * TD + d);
  ushort4v b0 = *(const ushort4v*)(ys  + (size_t)s1 * TD + d);
  ushort4v b1 = *(const ushort4v*)(ys1 + (size_t)s1 * TD + d);
  float* o = out + (size_t)t * TD + d;
  fvec4 c = *(const fvec4*)o;
#pragma unroll
  for (int j = 0; j < 4; ++j)
    c[j] += bf2f(a0[j]) + bf2f(a1[j]) + bf2f(b0[j]) + bf2f(b1[j]);
  *(fvec4*)o = c;
  if (t == 0 && threadIdx.x == 0) {
    float a = 0.f;
    for (int e2 = 0; e2 < TE; ++e2)
      a += ((float)counts[e2] / (float)TT) * (p_sum[e2] / (float)TT);
    out[(size_t)TT * TD] = (float)TE * a;
  }
}

// ---------------- router: per-block LDS aggregation + fused h2 (bf16 rmsnorm) write
__global__ __launch_bounds__(256)
void router_kernel(const float* __restrict__ X1, const float* __restrict__ N2W,
                   const float* __restrict__ RW, const float* __restrict__ RB,
                   int* __restrict__ top_e, float* __restrict__ top_g,
                   int* __restrict__ counts, float* __restrict__ p_sum,
                   unsigned short* __restrict__ h2) {
  __shared__ float s_psum[TE];
  __shared__ int s_cnt[TE];
  if (threadIdx.x < TE) { s_psum[threadIdx.x] = 0.f; s_cnt[threadIdx.x] = 0; }
  __syncthreads();
  int lane = threadIdx.x & 63, wave = threadIdx.x >> 6;
  for (int it = 0; it < 16; ++it) {
    int t = (blockIdx.x * 4 + wave) * 16 + it;
    const float* xr = X1 + (size_t)t * TD;
    float vals[16]; float ss = 0.f;
#pragma unroll
    for (int i = 0; i < 16; ++i) { float xv = xr[i * 64 + lane]; vals[i] = xv; ss += xv * xv; }
#pragma unroll
    for (int msk = 1; msk < 64; msk <<= 1) ss += __shfl_xor(ss, msk);
    float rs = rsqrtf(ss * (1.0f / TD) + 1e-6f);
    float acc[TE] = {};
#pragma unroll
    for (int i = 0; i < 16; ++i) {
      int d = i * 64 + lane;
      float nv = vals[i] * rs * N2W[d];
      h2[(size_t)t * TD + d] = f2bf(nv);     // fused rmsnorm output (MoE expert input)
      const float* rwp = RW + (size_t)d * TE;
#pragma unroll
      for (int e2 = 0; e2 < TE; ++e2) acc[e2] += nv * rwp[e2];
    }
#pragma unroll
    for (int msk = 1; msk < 64; msk <<= 1)
#pragma unroll
      for (int e2 = 0; e2 < TE; ++e2) acc[e2] += __shfl_xor(acc[e2], msk);
    if (lane == 0) {
      float lg[TE]; float mx = -1e30f;
      for (int e2 = 0; e2 < TE; ++e2) { lg[e2] = acc[e2] + RB[e2]; mx = fmaxf(mx, lg[e2]); }
      float sum = 0.f, pe[TE];
      for (int e2 = 0; e2 < TE; ++e2) { pe[e2] = expf(lg[e2] - mx); sum += pe[e2]; }
      float inv = 1.0f / sum;
      for (int e2 = 0; e2 < TE; ++e2) atomicAdd(&s_psum[e2], pe[e2] * inv);
      int i1 = 0;
      for (int e2 = 1; e2 < TE; ++e2) if (lg[e2] > lg[i1]) i1 = e2;
      int i2 = (i1 == 0) ? 1 : 0;
      for (int e2 = 0; e2 < TE; ++e2) if (e2 != i1 && lg[e2] > lg[i2]) i2 = e2;
      float g1 = pe[i1], g2 = pe[i2], gs = g1 + g2;
      top_e[t * 2] = i1; top_e[t * 2 + 1] = i2;
      top_g[t * 2] = g1 / gs; top_g[t * 2 + 1] = g2 / gs;
      atomicAdd(&s_cnt[i1], 1); atomicAdd(&s_cnt[i2], 1);
    }
  }
  __syncthreads();
  if (threadIdx.x < TE) {
    atomicAdd(&p_sum[threadIdx.x], s_psum[threadIdx.x]);
    atomicAdd(&counts[threadIdx.x], s_cnt[threadIdx.x]);
  }
}

__global__ void zero_meta_kernel(int* counts, float* p_sum) {
  int t = threadIdx.x;
  if (t < TE) { counts[t] = 0; p_sum[t] = 0.f; }
}

__global__ void offsets_kernel(const int* counts, int* offs, int* cursor) {
  if (threadIdx.x == 0) {
    int o = 0;
    for (int e2 = 0; e2 < TE; ++e2) { offs[e2] = o; o += counts[e2]; }
  }
  if (threadIdx.x < TE) cursor[threadIdx.x] = 0;
}

// ---------------- fill: per-block LDS histogram + range-reserve; records slots
__global__ __launch_bounds__(256)
void fill_kernel(const int* __restrict__ top_e, const float* __restrict__ top_g,
                 const int* __restrict__ offs, int* __restrict__ cursor,
                 int* __restrict__ token_perm, float* __restrict__ gate_perm,
                 int* __restrict__ tslot) {
  __shared__ int s_cnt[TE], s_base[TE];
  if (threadIdx.x < TE) s_cnt[threadIdx.x] = 0;
  __syncthreads();
  int t = blockIdx.x * 256 + threadIdx.x;
  int e0 = top_e[t * 2], e1 = top_e[t * 2 + 1];
  int r0 = atomicAdd(&s_cnt[e0], 1);
  int r1 = atomicAdd(&s_cnt[e1], 1);
  __syncthreads();
  if (threadIdx.x < TE)
    s_base[threadIdx.x] = atomicAdd(&cursor[threadIdx.x], s_cnt[threadIdx.x]);
  __syncthreads();
  int p0 = offs[e0] + s_base[e0] + r0;
  int p1 = offs[e1] + s_base[e1] + r1;
  token_perm[p0] = t; gate_perm[p0] = top_g[t * 2];
  token_perm[p1] = t; gate_perm[p1] = top_g[t * 2 + 1];
  tslot[t * 2] = p0; tslot[t * 2 + 1] = p1;
}

extern "C" void kernel_launch(void* const* d_in, const int* in_sizes, int n_in,
                              void* d_out, int out_size, void* d_ws, size_t ws_size,
                              hipStream_t stream) {
  const float* x     = (const float*)d_in[0];
  const float* n1w   = (const float*)d_in[1];
  const float* n2w   = (const float*)d_in[2];
  const float* w_qkv = (const float*)d_in[3];
  const float* b_qkv = (const float*)d_in[4];
  const float* w_o   = (const float*)d_in[5];
  const float* b_o   = (const float*)d_in[6];
  const float* rw    = (const float*)d_in[7];
  const float* rb    = (const float*)d_in[8];
  const float* w1    = (const float*)d_in[9];
  const float* b1    = (const float*)d_in[10];
  const float* w2    = (const float*)d_in[11];
  const float* b2    = (const float*)d_in[12];
  float* out = (float*)d_out;
  char* ws = (char*)d_ws;

  size_t o = 0;
  auto give = [&](size_t bytes) -> char* {
    char* p = ws + o;
    o += (bytes + 255) & ~(size_t)255;
    return p;
  };
  unsigned short* w1T = (unsigned short*)give(8ull * 4096 * 1024 * 2);   // 64MB
  unsigned short* w2T = (unsigned short*)give(8ull * 1024 * 4096 * 2);   // 64MB
  unsigned short* wo0 = (unsigned short*)give(1024ull * 1024 * 2);
  unsigned short* wo1 = (unsigned short*)give(1024ull * 1024 * 2);
  unsigned short* h2  = (unsigned short*)give((size_t)TT * TD * 2);      // 8MB
  int*   counts = (int*)give(TE * 4);
  int*   cursor = (int*)give(TE * 4);
  int*   offs   = (int*)give(TE * 4);
  float* psum   = (float*)give(TE * 4);
  int*   top_e  = (int*)give(2ull * TT * 4);
  float* top_g  = (float*)give(2ull * TT * 4);
  int*   tperm  = (int*)give(2ull * TT * 4);
  float* gperm  = (float*)give(2ull * TT * 4);
  int*   tslot  = (int*)give(2ull * TT * 4);
  unsigned short* wq0 = (unsigned short*)give(3072ull * 1024 * 2);
  unsigned short* wq1 = (unsigned short*)give(3072ull * 1024 * 2);
  unsigned short* ysb = (unsigned short*)give(2ull * 2 * TT * TD * 2);   // 32MB (2 K-halves, bf16)
  // pool B: h1 pair (dead after gemm2<0>) aliased with ao pair (dead after gemm2<1>)
  // then reused as h2p packed MoE input (born after fill)
  char* poolB = give(2ull * TT * TD * 2);                                // 16MB
  unsigned short* h10 = (unsigned short*)poolB;
  unsigned short* h11 = (unsigned short*)(poolB + (size_t)TT * TD * 2);
  unsigned short* ao0 = h10; unsigned short* ao1 = h11;
  unsigned short* h2p = (unsigned short*)poolB;                          // [2TT][TD] bf16
  // pool C: qkv split pair (dead after attn) aliased with he (born at MoE up)
  char* poolC = give(64ull * 1024 * 1024);                               // 64MB
  unsigned short* qs0 = (unsigned short*)poolC;
  unsigned short* qs1 = (unsigned short*)(poolC + 3ull * PSTR * 2);
  unsigned short* he  = (unsigned short*)poolC;                          // [2TT][TF] bf16

  // weight prep (64x64 transpose tiles)
  tcvt_split_kernel<<<dim3(48, 16, 1), 256, 0, stream>>>(w_qkv, wq0, wq1, 1024, 3072);
  tcvt_split_kernel<<<dim3(16, 16, 1), 256, 0, stream>>>(w_o, wo0, wo1, 1024, 1024);
  tcvt_kernel<<<dim3(64, 16, 8), 256, 0, stream>>>(w1, w1T, 1024, 4096);
  tcvt_kernel<<<dim3(16, 64, 8), 256, 0, stream>>>(w2, w2T, 4096, 1024);

  // attention path (2-way split, 3-product; all operands pre-split)
  rmsnorm_split_kernel<<<dim3(TT), 256, 0, stream>>>(x, n1w, h10, h11);
  gemm2<0><<<dim3(24, 32, 1), 256, 0, stream>>>(
      h10, h11, wq0, wq1, b_qkv, 1024, nullptr, nullptr, qs0, qs1);
  attn2_kernel<<<dim3(8, 32, 1), 512, 0, stream>>>(qs0, qs1, ao0, ao1);
  gemm2<1><<<dim3(8, 32, 1), 256, 0, stream>>>(
      ao0, ao1, wo0, wo1, b_o, 1024, out, x, nullptr, nullptr);

  // MoE path (bf16); router fuses the rmsnorm h2 write
  zero_meta_kernel<<<dim3(1), 64, 0, stream>>>(counts, psum);
  router_kernel<<<dim3(64), 256, 0, stream>>>(out, n2w, rw, rb, top_e, top_g, counts, psum, h2);
  offsets_kernel<<<dim3(1), 64, 0, stream>>>(counts, offs, cursor);
  fill_kernel<<<dim3(TT / 256), 256, 0, stream>>>(top_e, top_g, offs, cursor, tperm, gperm, tslot);
  moe_gather_kernel<<<dim3(2 * TT), 256, 0, stream>>>(h2, tperm, h2p);
  gemm_bt<2><<<dim3(32, 32, 8), 256, 0, stream>>>(
      h2p, w1T, b1, 4096, 1024, 1024, nullptr, he, offs, counts, gperm);
  gemm_bt<3><<<dim3(8, 32, 16), 256, 0, stream>>>(
      he, w2T, b2, 1024, 2048, 4096, ysb, nullptr, offs, counts, gperm);
  moe_reduce_kernel<<<dim3(TT), 256, 0, stream>>>(ysb, tslot, out, counts, psum);
}

// Round 18
// 715.598 us; speedup vs baseline: 1.0827x; 1.0167x over previous
//
#include <hip/hip_runtime.h>
#include <math.h>

#define TB 2
#define TS 2048
#define TD 1024
#define TH 16
#define TDH 64
#define TF 4096
#define TE 8
#define TT 4096                 // B*S tokens
#define PSTR (TB*TH*TS*TDH)     // 4194304 elements per q/k/v part

typedef __attribute__((ext_vector_type(8))) __bf16 bf16x8;
typedef __attribute__((ext_vector_type(4))) float f32x4;
typedef __attribute__((ext_vector_type(8))) short short8;
typedef __attribute__((ext_vector_type(4))) unsigned short ushort4v;
typedef __attribute__((ext_vector_type(4))) float fvec4;

__device__ inline unsigned short f2bf(float f) {
  union { float f; unsigned int u; } v; v.f = f;
  unsigned int u = v.u;
  unsigned int r = (u + 0x7FFFu + ((u >> 16) & 1u)) >> 16;
  return (unsigned short)r;
}
__device__ inline float bf2f(unsigned short h) {
  union { unsigned int u; float f; } v; v.u = ((unsigned int)h) << 16; return v.f;
}
// 2-way bf16 split: h+m reproduces ~17 mantissa bits (residual ~2^-18)
__device__ inline void split2(float x, unsigned short& h, unsigned short& m) {
  h = f2bf(x);
  m = f2bf(x - bf2f(h));
}

__device__ inline f32x4 mfma_bf16(short8 a, short8 b, f32x4 c) {
  return __builtin_amdgcn_mfma_f32_16x16x32_bf16(
      __builtin_bit_cast(bf16x8, a), __builtin_bit_cast(bf16x8, b), c, 0, 0, 0);
}

// async global->LDS, 16B per lane. LDS dest = wave-uniform base + lane*16.
__device__ inline void gload16(const void* g, void* l) {
  __builtin_amdgcn_global_load_lds(
      (const __attribute__((address_space(1))) void*)g,
      (__attribute__((address_space(3))) void*)l, 16, 0, 0);
}

// fast exact-GELU: erf via Abramowitz-Stegun 7.1.26 (|abs err| < 1.5e-7)
__device__ inline float gelu_f(float v) {
  float ax = fabsf(v) * 0.70710678118654752f;
  float t = __builtin_amdgcn_rcpf(1.0f + 0.3275911f * ax);
  float poly = ((((1.061405429f * t - 1.453152027f) * t + 1.421413741f) * t
                 - 0.284496736f) * t + 0.254829592f) * t;
  float er = 1.0f - poly * __expf(-ax * ax);
  er = copysignf(er, v);
  return 0.5f * v * (1.0f + er);
}

// ---------------- transpose + f32->bf16 convert: in [R,C] f32 -> out [C,R] bf16
// 64x64 tiles: 256B-contiguous loads, 128B-contiguous bf16 stores.
__global__ __launch_bounds__(256)
void tcvt_kernel(const float* __restrict__ In, unsigned short* __restrict__ Out,
                 int R, int C) {
  __shared__ float tile[64][65];
  In  += (size_t)blockIdx.z * R * C;
  Out += (size_t)blockIdx.z * R * C;
  int c0 = blockIdx.x * 64, r0 = blockIdx.y * 64;
  int tx = threadIdx.x & 63, ty = threadIdx.x >> 6;  // ty 0..3
#pragma unroll
  for (int i = 0; i < 16; ++i) {
    int row = ty + 4 * i;
    tile[row][tx] = In[(size_t)(r0 + row) * C + c0 + tx];
  }
  __syncthreads();
#pragma unroll
  for (int i = 0; i < 16; ++i) {
    int orow = ty + 4 * i;
    Out[(size_t)(c0 + orow) * R + r0 + tx] = f2bf(tile[tx][orow]);
  }
}

// ---------------- transpose + 2-way split: in [R,C] f32 -> 2x [C,R] bf16 (64x64)
__global__ __launch_bounds__(256)
void tcvt_split_kernel(const float* __restrict__ In,
                       unsigned short* __restrict__ O0,
                       unsigned short* __restrict__ O1, int R, int C) {
  __shared__ float tile[64][65];
  int c0 = blockIdx.x * 64, r0 = blockIdx.y * 64;
  int tx = threadIdx.x & 63, ty = threadIdx.x >> 6;
#pragma unroll
  for (int i = 0; i < 16; ++i) {
    int row = ty + 4 * i;
    tile[row][tx] = In[(size_t)(r0 + row) * C + c0 + tx];
  }
  __syncthreads();
#pragma unroll
  for (int i = 0; i < 16; ++i) {
    int orow = ty + 4 * i;
    float v = tile[tx][orow];
    unsigned short h, m; split2(v, h, m);
    size_t idx = (size_t)(c0 + orow) * R + r0 + tx;
    O0[idx] = h; O1[idx] = m;
  }
}

// ---------------- RMSNorm f32 in -> pre-split bf16 pair; block 0 zeros MoE meta
__global__ __launch_bounds__(256)
void rmsnorm_split_kernel(const float* __restrict__ X, const float* __restrict__ W,
                          unsigned short* __restrict__ O0,
                          unsigned short* __restrict__ O1,
                          int* __restrict__ counts, float* __restrict__ p_sum,
                          int* __restrict__ cursor) {
  int row = blockIdx.x;
  int tid = threadIdx.x;
  int lane = tid & 63, wave = tid >> 6;
  if (row == 0 && tid < TE) { counts[tid] = 0; p_sum[tid] = 0.f; cursor[tid] = 0; }
  const float* xr = X + (size_t)row * TD;
  fvec4 v = *(const fvec4*)(xr + tid * 4);
  float ss = v[0]*v[0] + v[1]*v[1] + v[2]*v[2] + v[3]*v[3];
#pragma unroll
  for (int msk = 1; msk < 64; msk <<= 1) ss += __shfl_xor(ss, msk);
  __shared__ float red[4];
  if (lane == 0) red[wave] = ss;
  __syncthreads();
  ss = red[0] + red[1] + red[2] + red[3];
  float rs = rsqrtf(ss * (1.0f / TD) + 1e-6f);
  fvec4 wv = *(const fvec4*)(W + tid * 4);
  ushort4v o0, o1;
#pragma unroll
  for (int j = 0; j < 4; ++j) {
    unsigned short h, m; split2(v[j] * rs * wv[j], h, m);
    o0[j] = h; o1[j] = m;
  }
  size_t idx = (size_t)row * TD + tid * 4;
  *(ushort4v*)(O0 + idx) = o0;
  *(ushort4v*)(O1 + idx) = o1;
}

// ---------------- high-precision GEMM: A,B pre-split bf16 pairs, 3-product split.
// gload_lds staging, dbuf, SINGLE-barrier pipeline (stage-top, drain-after-compute).
// MODE 0: QKV -> scatter pairs: Q,K at [bh][s][dh]; V transposed [bh][dh][s]
// MODE 1: f32 out = acc + bias + resid
template<int MODE>
__global__ __launch_bounds__(256)
void gemm2(const unsigned short* __restrict__ A0,
           const unsigned short* __restrict__ A1,
           const unsigned short* __restrict__ B0,
           const unsigned short* __restrict__ B1,
           const float* __restrict__ bias, int Kd,
           float* __restrict__ outF, const float* __restrict__ resid,
           unsigned short* __restrict__ S0,
           unsigned short* __restrict__ S1) {
  __shared__ __align__(16) unsigned short As0[2][4096], As1[2][4096];
  __shared__ __align__(16) unsigned short Bs0[2][4096], Bs1[2][4096];
  const int tid = threadIdx.x;
  const int lane = tid & 63;
  const int w = tid >> 6;
  const int wr = w >> 1, wc = w & 1;
  const int g = lane >> 4;
  const int l15 = lane & 15;
  const int m0 = blockIdx.y * 128;
  const int n0 = blockIdx.x * 128;

  const int c_swz = (lane & 3) ^ ((lane >> 3) & 3);
  const unsigned short *a0p[2], *a1p[2], *b0p[2], *b1p[2];
  int ldsrow[2];
#pragma unroll
  for (int j = 0; j < 2; ++j) {
    int r16 = w * 2 + j;
    int r = r16 * 16 + (lane >> 2);
    a0p[j] = A0 + (size_t)(m0 + r) * Kd + c_swz * 8;
    a1p[j] = A1 + (size_t)(m0 + r) * Kd + c_swz * 8;
    b0p[j] = B0 + (size_t)(n0 + r) * Kd + c_swz * 8;
    b1p[j] = B1 + (size_t)(n0 + r) * Kd + c_swz * 8;
    ldsrow[j] = r16 * 512;
  }

#define G2_STAGE(p, koff)                              \
  {                                                    \
    _Pragma("unroll")                                  \
    for (int j = 0; j < 2; ++j) {                      \
      gload16(a0p[j] + (koff), &As0[p][ldsrow[j]]);    \
      gload16(a1p[j] + (koff), &As1[p][ldsrow[j]]);    \
      gload16(b0p[j] + (koff), &Bs0[p][ldsrow[j]]);    \
      gload16(b1p[j] + (koff), &Bs1[p][ldsrow[j]]);    \
    }                                                  \
  }

  f32x4 acc[4][4] = {};
  const int nt = Kd >> 5;

  G2_STAGE(0, 0);
  asm volatile("s_waitcnt vmcnt(0)" ::: "memory");
  __builtin_amdgcn_s_barrier();
  for (int t = 0; t < nt; ++t) {
    const int p = t & 1;
    if (t + 1 < nt) G2_STAGE(p ^ 1, (t + 1) * 32);

    short8 a0f[4], a1f[4], b0f[4], b1f[4];
#pragma unroll
    for (int mi = 0; mi < 4; ++mi) {
      int row = wr * 64 + mi * 16 + l15;
      int off = (row * 64 + g * 16) ^ (((row >> 1) & 3) << 4);
      a0f[mi] = *(const short8*)((const char*)As0[p] + off);
      a1f[mi] = *(const short8*)((const char*)As1[p] + off);
    }
#pragma unroll
    for (int ni = 0; ni < 4; ++ni) {
      int row = wc * 64 + ni * 16 + l15;
      int off = (row * 64 + g * 16) ^ (((row >> 1) & 3) << 4);
      b0f[ni] = *(const short8*)((const char*)Bs0[p] + off);
      b1f[ni] = *(const short8*)((const char*)Bs1[p] + off);
    }
#pragma unroll
    for (int mi = 0; mi < 4; ++mi)
#pragma unroll
      for (int ni = 0; ni < 4; ++ni) {
        f32x4 tacc = acc[mi][ni];
        tacc = mfma_bf16(a0f[mi], b0f[ni], tacc);
        tacc = mfma_bf16(a0f[mi], b1f[ni], tacc);
        tacc = mfma_bf16(a1f[mi], b0f[ni], tacc);
        acc[mi][ni] = tacc;
      }
    // drain next tile's loads (issued at loop top, hidden under compute), one barrier
    asm volatile("s_waitcnt vmcnt(0)" ::: "memory");
    __builtin_amdgcn_s_barrier();
  }
#undef G2_STAGE

#pragma unroll
  for (int mi = 0; mi < 4; ++mi) {
#pragma unroll
    for (int ni = 0; ni < 4; ++ni) {
      int n = n0 + wc * 64 + ni * 16 + l15;
      float bv = bias[n];
      if (MODE == 0) {
        int part = n >> 10, d = n & 1023, hh = d >> 6, dh = d & 63;
        int s0r = m0 + wr * 64 + mi * 16 + g * 4;
        int b = s0r >> 11, s_ = s0r & 2047;
        int bh = b * TH + hh;
        if (part < 2) {
          size_t base = (size_t)part * PSTR + (size_t)bh * (TS * TDH) + (size_t)s_ * TDH + dh;
#pragma unroll
          for (int r = 0; r < 4; ++r) {
            unsigned short h, m; split2(acc[mi][ni][r] + bv, h, m);
            size_t idx = base + (size_t)r * TDH;
            S0[idx] = h; S1[idx] = m;
          }
        } else {
          ushort4v o0, o1;
#pragma unroll
          for (int r = 0; r < 4; ++r) {
            unsigned short h, m; split2(acc[mi][ni][r] + bv, h, m);
            o0[r] = h; o1[r] = m;
          }
          size_t idx = 2 * (size_t)PSTR + (size_t)bh * (TS * TDH) + (size_t)dh * TS + s_;
          *(ushort4v*)(S0 + idx) = o0;
          *(ushort4v*)(S1 + idx) = o1;
        }
      } else {
#pragma unroll
        for (int r = 0; r < 4; ++r) {
          int m = m0 + wr * 64 + mi * 16 + g * 4 + r;
          size_t idx = (size_t)m * TD + n;
          outF[idx] = acc[mi][ni][r] + bv + resid[idx];
        }
      }
    }
  }
}

// ---------------- flash attention, causal, 3-product split, pre-split bf16 I/O
// 8 waves / 512 threads; block handles q-tiles bx and 15-bx (heavy+light fused).
// K/V staged via global_load_lds with pre-swizzled source (linear LDS dest).
__global__ __launch_bounds__(512, 4)
void attn2_kernel(const unsigned short* __restrict__ S0,
                  const unsigned short* __restrict__ S1,
                  unsigned short* __restrict__ A0,
                  unsigned short* __restrict__ A1) {
  __shared__ __align__(16) unsigned short Kt0[4096], Kt1[4096];
  __shared__ __align__(16) unsigned short Vt0[4096], Vt1[4096];
  __shared__ __align__(16) char Pt0[16384], Pt1[16384];

  const int tid = threadIdx.x;
  const int lane = tid & 63;
  const int wave = tid >> 6;          // 0..7
  const int g = lane >> 4, l15 = lane & 15;

  const int bh = blockIdx.y;
  const int b = bh >> 4, hh = bh & 15;

  const size_t qbase = (size_t)bh * TS * TDH;
  const size_t kbase = (size_t)PSTR + qbase;
  const size_t vbase = 2 * (size_t)PSTR + qbase;   // [dh][s] layout

  const int srow = wave * 8 + (lane >> 3);
  const int scw = (lane & 7) ^ (srow & 7);
  unsigned short* const kdst0 = Kt0 + wave * 512;   // 8 rows * 64 elems
  unsigned short* const kdst1 = Kt1 + wave * 512;
  unsigned short* const vdst0 = Vt0 + wave * 512;
  unsigned short* const vdst1 = Vt1 + wave * 512;

  for (int half = 0; half < 2; ++half) {
    const int qtb = half ? (15 - (int)blockIdx.x) : (int)blockIdx.x;
    const int qlo = qtb * 128 + wave * 16;         // wave's first q row

    short8 aq0[2], aq1[2];
#pragma unroll
    for (int c = 0; c < 2; ++c) {
      size_t qo = qbase + (size_t)(qlo + l15) * TDH + c * 32 + g * 8;
      aq0[c] = *(const short8*)(S0 + qo);
      aq1[c] = *(const short8*)(S1 + qo);
    }

    f32x4 accv[4] = {};
    float m_[4] = {-1e30f, -1e30f, -1e30f, -1e30f};
    float l_[4] = {0.f, 0.f, 0.f, 0.f};

    const int ktmax = 2 * qtb + 1;
    for (int kt = 0; kt <= ktmax; ++kt) {
      __syncthreads();   // prior compute done reading LDS
      {
        size_t kg = kbase + (size_t)(kt * 64 + srow) * TDH + scw * 8;
        gload16(S0 + kg, kdst0);
        gload16(S1 + kg, kdst1);
        size_t vg = vbase + (size_t)srow * TS + kt * 64 + scw * 8;
        gload16(S0 + vg, vdst0);
        gload16(S1 + vg, vdst1);
      }
      __syncthreads();   // drains vmcnt(0): tile resident

      if (kt * 64 > qlo + 15) continue;   // above diagonal for this wave
      const bool needmask = (kt * 64 + 63 > qlo);

      f32x4 sf[4] = {};
      __builtin_amdgcn_s_setprio(1);
#pragma unroll
      for (int kb = 0; kb < 4; ++kb) {
#pragma unroll
        for (int c = 0; c < 2; ++c) {
          int krow = kb * 16 + l15;
          int off = (krow * 128 + (c * 32 + g * 8) * 2) ^ ((krow & 7) << 4);
          short8 bk0 = *(const short8*)((const char*)Kt0 + off);
          short8 bk1 = *(const short8*)((const char*)Kt1 + off);
          f32x4 t = sf[kb];
          t = mfma_bf16(aq0[c], bk0, t);
          t = mfma_bf16(aq0[c], bk1, t);
          t = mfma_bf16(aq1[c], bk0, t);
          sf[kb] = t;
        }
      }
      __builtin_amdgcn_s_setprio(0);

      float pv[4][4];
#pragma unroll
      for (int r = 0; r < 4; ++r) {
        float s0 = sf[0][r] * 0.125f, s1 = sf[1][r] * 0.125f;
        float s2 = sf[2][r] * 0.125f, s3 = sf[3][r] * 0.125f;
        if (needmask) {
          int qg = qlo + g * 4 + r;
          int k0g = kt * 64 + l15;
          if (k0g      > qg) s0 = -1e30f;
          if (k0g + 16 > qg) s1 = -1e30f;
          if (k0g + 32 > qg) s2 = -1e30f;
          if (k0g + 48 > qg) s3 = -1e30f;
        }
        float mx = fmaxf(fmaxf(s0, s1), fmaxf(s2, s3));
#pragma unroll
        for (int msk = 1; msk < 16; msk <<= 1) mx = fmaxf(mx, __shfl_xor(mx, msk));
        float nm = fmaxf(m_[r], mx);
        float sc = __expf(m_[r] - nm);
        float p0 = __expf(s0 - nm), p1 = __expf(s1 - nm);
        float p2 = __expf(s2 - nm), p3 = __expf(s3 - nm);
        float rs = p0 + p1 + p2 + p3;
#pragma unroll
        for (int msk = 1; msk < 16; msk <<= 1) rs += __shfl_xor(rs, msk);
        m_[r] = nm;
        l_[r] = l_[r] * sc + rs;
#pragma unroll
        for (int dhb = 0; dhb < 4; ++dhb) accv[dhb][r] *= sc;
        pv[0][r] = p0; pv[1][r] = p1; pv[2][r] = p2; pv[3][r] = p3;
      }

      char* P0 = Pt0 + wave * 2048;
      char* P1 = Pt1 + wave * 2048;
#pragma unroll
      for (int kb = 0; kb < 4; ++kb) {
#pragma unroll
        for (int r = 0; r < 4; ++r) {
          int prow = g * 4 + r;
          int key = kb * 16 + l15;
          int off = (prow * 128 + key * 2) ^ ((prow & 7) << 4);
          unsigned short h, m; split2(pv[kb][r], h, m);
          *(unsigned short*)(P0 + off) = h;
          *(unsigned short*)(P1 + off) = m;
        }
      }
      short8 pa0[2], pa1[2];
#pragma unroll
      for (int c = 0; c < 2; ++c) {
        int off = (l15 * 128 + (c * 32 + g * 8) * 2) ^ ((l15 & 7) << 4);
        pa0[c] = *(const short8*)(P0 + off);
        pa1[c] = *(const short8*)(P1 + off);
      }
      __builtin_amdgcn_s_setprio(1);
#pragma unroll
      for (int dhb = 0; dhb < 4; ++dhb) {
#pragma unroll
        for (int c = 0; c < 2; ++c) {
          int dh = dhb * 16 + l15;
          int off = (dh * 128 + (c * 32 + g * 8) * 2) ^ ((dh & 7) << 4);
          short8 bv0 = *(const short8*)((const char*)Vt0 + off);
          short8 bv1 = *(const short8*)((const char*)Vt1 + off);
          f32x4 t = accv[dhb];
          t = mfma_bf16(pa0[c], bv0, t);
          t = mfma_bf16(pa0[c], bv1, t);
          t = mfma_bf16(pa1[c], bv0, t);
          accv[dhb] = t;
        }
      }
      __builtin_amdgcn_s_setprio(0);
    }

#pragma unroll
    for (int dhb = 0; dhb < 4; ++dhb) {
#pragma unroll
      for (int r = 0; r < 4; ++r) {
        int srow2 = qlo + g * 4 + r;
        int col = hh * 64 + dhb * 16 + l15;
        unsigned short h, m; split2(accv[dhb][r] / l_[r], h, m);
        size_t idx = ((size_t)(b * TS + srow2)) * TD + col;
        A0[idx] = h; A1[idx] = m;
      }
    }
  }
}

// ---------------- MoE GEMM (plain bf16), gload_lds + dbuf + SINGLE-barrier pipeline.
// Expert offset computed locally from seg_cnt prefix (no offs buffer).
// MODE 2: up-proj, A = h2 token-indexed via token_perm (tok LDS), gelu -> he bf16.
// MODE 3: down-proj SPLIT-K (blockIdx.z = e*2+ks), A = he packed by slot,
//         gated bf16 partials -> ysb[ks][slot][n] (no atomics).
template<int MODE>
__global__ __launch_bounds__(256)
void gemm_bt(const unsigned short* __restrict__ A,
             const unsigned short* __restrict__ Bt,
             const float* __restrict__ bias,
             int N, int Kd, int Kstride,
             unsigned short* __restrict__ ysb,
             unsigned short* __restrict__ outH,
             const int* __restrict__ seg_cnt,
             const int* __restrict__ token_perm,
             const float* __restrict__ gate_perm) {
  __shared__ __align__(16) unsigned short As[2][4096];   // [128][32] swizzled
  __shared__ __align__(16) unsigned short Bs[2][4096];
  __shared__ int tok[128];

  const int tid = threadIdx.x;
  const int lane = tid & 63;
  const int w = tid >> 6;
  const int wr = w >> 1, wc = w & 1;
  const int g = lane >> 4;
  const int l15 = lane & 15;

  const int e  = (MODE == 3) ? ((int)blockIdx.z >> 1) : (int)blockIdx.z;
  const int ks = (MODE == 3) ? ((int)blockIdx.z & 1) : 0;
  const int koff = ks * Kd;
  const int m0 = blockIdx.y * 128;
  const int n0 = blockIdx.x * 128;
  int off = 0;
#pragma unroll
  for (int i = 0; i < TE; ++i) off += (i < e) ? seg_cnt[i] : 0;
  const int Mrows = seg_cnt[e];
  if (m0 >= Mrows) return;
  Bt += (size_t)e * N * Kstride;
  bias += (size_t)e * N;

  if (MODE == 2) {
    if (tid < 128) {
      int r = m0 + tid;
      int rc = (r < Mrows) ? r : (Mrows - 1);
      tok[tid] = token_perm[off + rc];
    }
    __syncthreads();
  }

  const int c_swz = (lane & 3) ^ ((lane >> 3) & 3);
  const unsigned short* aptr[2];
  const unsigned short* bptr[2];
  int ldsrow[2];
#pragma unroll
  for (int j = 0; j < 2; ++j) {
    int r16 = w * 2 + j;
    int r = r16 * 16 + (lane >> 2);
    if (MODE == 2) {
      aptr[j] = A + (size_t)tok[r] * Kstride + c_swz * 8;
    } else {
      int rc = (m0 + r < Mrows) ? (m0 + r) : (Mrows - 1);
      aptr[j] = A + (size_t)(off + rc) * Kstride + koff + c_swz * 8;
    }
    bptr[j] = Bt + (size_t)(n0 + r) * Kstride + koff + c_swz * 8;
    ldsrow[j] = r16 * 512;
  }

#define GB_STAGE(p, ko)                             \
  {                                                 \
    _Pragma("unroll")                               \
    for (int j = 0; j < 2; ++j) {                   \
      gload16(aptr[j] + (ko), &As[p][ldsrow[j]]);   \
      gload16(bptr[j] + (ko), &Bs[p][ldsrow[j]]);   \
    }                                               \
  }

  f32x4 acc[4][4] = {};
  const int nt = Kd >> 5;

  GB_STAGE(0, 0);
  asm volatile("s_waitcnt vmcnt(0)" ::: "memory");
  __builtin_amdgcn_s_barrier();
  for (int t = 0; t < nt; ++t) {
    const int p = t & 1;
    if (t + 1 < nt) GB_STAGE(p ^ 1, (t + 1) * 32);

    short8 af[4], bfr[4];
#pragma unroll
    for (int mi = 0; mi < 4; ++mi) {
      int row = wr * 64 + mi * 16 + l15;
      int o2 = (row * 64 + g * 16) ^ (((row >> 1) & 3) << 4);
      af[mi] = *(const short8*)((const char*)As[p] + o2);
    }
#pragma unroll
    for (int ni = 0; ni < 4; ++ni) {
      int row = wc * 64 + ni * 16 + l15;
      int o2 = (row * 64 + g * 16) ^ (((row >> 1) & 3) << 4);
      bfr[ni] = *(const short8*)((const char*)Bs[p] + o2);
    }
#pragma unroll
    for (int mi = 0; mi < 4; ++mi)
#pragma unroll
      for (int ni = 0; ni < 4; ++ni)
        acc[mi][ni] = mfma_bf16(af[mi], bfr[ni], acc[mi][ni]);
    // drain next tile's loads (issued at loop top, hidden under compute), one barrier
    asm volatile("s_waitcnt vmcnt(0)" ::: "memory");
    __builtin_amdgcn_s_barrier();
  }
#undef GB_STAGE

#pragma unroll
  for (int mi = 0; mi < 4; ++mi) {
#pragma unroll
    for (int ni = 0; ni < 4; ++ni) {
      int n = n0 + wc * 64 + ni * 16 + l15;
      float bv = (MODE == 3 && ks != 0) ? 0.0f : bias[n];
#pragma unroll
      for (int r = 0; r < 4; ++r) {
        int mloc = m0 + wr * 64 + mi * 16 + g * 4 + r;
        if (mloc >= Mrows) continue;
        float val = acc[mi][ni][r] + bv;
        if (MODE == 2) {
          outH[(size_t)(off + mloc) * TF + n] = f2bf(gelu_f(val));
        } else {
          float gv = gate_perm[off + mloc];
          ysb[(size_t)ks * (2ull * TT * TD) + (size_t)(off + mloc) * TD + n] =
              f2bf(gv * val);
        }
      }
    }
  }
}

// ---------------- MoE reduce: out[t] += sum of 4 bf16 partials; block 0 writes aux
__global__ __launch_bounds__(256)
void moe_reduce_kernel(const unsigned short* __restrict__ ys, const int* __restrict__ tslot,
                       float* __restrict__ out,
                       const int* __restrict__ counts, const float* __restrict__ p_sum) {
  int t = blockIdx.x;
  int d = threadIdx.x * 4;
  int s0 = tslot[t * 2], s1 = tslot[t * 2 + 1];
  const unsigned short* ys1 = ys + 2ull * TT * TD;
  ushort4v a0 = *(const ushort4v*)(ys  + (size_t)s0 * TD + d);
  ushort4v a1 = *(const ushort4v*)(ys1 + (size_t)s0 * TD + d);
  ushort4v b0 = *(const ushort4v*)(ys  + (size_t)s1 * TD + d);
  ushort4v b1 = *(const ushort4v*)(ys1 + (size_t)s1 * TD + d);
  float* o = out + (size_t)t * TD + d;
  fvec4 c = *(const fvec4*)o;
#pragma unroll
  for (int j = 0; j < 4; ++j)
    c[j] += bf2f(a0[j]) + bf2f(a1[j]) + bf2f(b0[j]) + bf2f(b1[j]);
  *(fvec4*)o = c;
  if (t == 0 && threadIdx.x == 0) {
    float a = 0.f;
    for (int e2 = 0; e2 < TE; ++e2)
      a += ((float)counts[e2] / (float)TT) * (p_sum[e2] / (float)TT);
    out[(size_t)TT * TD] = (float)TE * a;
  }
}

// ---------------- router: per-block LDS aggregation + fused h2 (bf16 rmsnorm) write
__global__ __launch_bounds__(256)
void router_kernel(const float* __restrict__ X1, const float* __restrict__ N2W,
                   const float* __restrict__ RW, const float* __restrict__ RB,
                   int* __restrict__ top_e, float* __restrict__ top_g,
                   int* __restrict__ counts, float* __restrict__ p_sum,
                   unsigned short* __restrict__ h2) {
  __shared__ float s_psum[TE];
  __shared__ int s_cnt[TE];
  if (threadIdx.x < TE) { s_psum[threadIdx.x] = 0.f; s_cnt[threadIdx.x] = 0; }
  __syncthreads();
  int lane = threadIdx.x & 63, wave = threadIdx.x >> 6;
  for (int it = 0; it < 16; ++it) {
    int t = (blockIdx.x * 4 + wave) * 16 + it;
    const float* xr = X1 + (size_t)t * TD;
    float vals[16]; float ss = 0.f;
#pragma unroll
    for (int i = 0; i < 16; ++i) { float xv = xr[i * 64 + lane]; vals[i] = xv; ss += xv * xv; }
#pragma unroll
    for (int msk = 1; msk < 64; msk <<= 1) ss += __shfl_xor(ss, msk);
    float rs = rsqrtf(ss * (1.0f / TD) + 1e-6f);
    float acc[TE] = {};
#pragma unroll
    for (int i = 0; i < 16; ++i) {
      int d = i * 64 + lane;
      float nv = vals[i] * rs * N2W[d];
      h2[(size_t)t * TD + d] = f2bf(nv);     // fused rmsnorm output (MoE expert input)
      const float* rwp = RW + (size_t)d * TE;
#pragma unroll
      for (int e2 = 0; e2 < TE; ++e2) acc[e2] += nv * rwp[e2];
    }
#pragma unroll
    for (int msk = 1; msk < 64; msk <<= 1)
#pragma unroll
      for (int e2 = 0; e2 < TE; ++e2) acc[e2] += __shfl_xor(acc[e2], msk);
    if (lane == 0) {
      float lg[TE]; float mx = -1e30f;
      for (int e2 = 0; e2 < TE; ++e2) { lg[e2] = acc[e2] + RB[e2]; mx = fmaxf(mx, lg[e2]); }
      float sum = 0.f, pe[TE];
      for (int e2 = 0; e2 < TE; ++e2) { pe[e2] = expf(lg[e2] - mx); sum += pe[e2]; }
      float inv = 1.0f / sum;
      for (int e2 = 0; e2 < TE; ++e2) atomicAdd(&s_psum[e2], pe[e2] * inv);
      int i1 = 0;
      for (int e2 = 1; e2 < TE; ++e2) if (lg[e2] > lg[i1]) i1 = e2;
      int i2 = (i1 == 0) ? 1 : 0;
      for (int e2 = 0; e2 < TE; ++e2) if (e2 != i1 && lg[e2] > lg[i2]) i2 = e2;
      float g1 = pe[i1], g2 = pe[i2], gs = g1 + g2;
      top_e[t * 2] = i1; top_e[t * 2 + 1] = i2;
      top_g[t * 2] = g1 / gs; top_g[t * 2 + 1] = g2 / gs;
      atomicAdd(&s_cnt[i1], 1); atomicAdd(&s_cnt[i2], 1);
    }
  }
  __syncthreads();
  if (threadIdx.x < TE) {
    atomicAdd(&p_sum[threadIdx.x], s_psum[threadIdx.x]);
    atomicAdd(&counts[threadIdx.x], s_cnt[threadIdx.x]);
  }
}

// ---------------- fill: per-block LDS histogram + range-reserve; local expert offsets
__global__ __launch_bounds__(256)
void fill_kernel(const int* __restrict__ top_e, const float* __restrict__ top_g,
                 const int* __restrict__ counts, int* __restrict__ cursor,
                 int* __restrict__ token_perm, float* __restrict__ gate_perm,
                 int* __restrict__ tslot) {
  __shared__ int s_cnt[TE], s_base[TE], s_off[TE];
  if (threadIdx.x < TE) {
    s_cnt[threadIdx.x] = 0;
    int o = 0;
    for (int i = 0; i < threadIdx.x; ++i) o += counts[i];
    s_off[threadIdx.x] = o;
  }
  __syncthreads();
  int t = blockIdx.x * 256 + threadIdx.x;
  int e0 = top_e[t * 2], e1 = top_e[t * 2 + 1];
  int r0 = atomicAdd(&s_cnt[e0], 1);
  int r1 = atomicAdd(&s_cnt[e1], 1);
  __syncthreads();
  if (threadIdx.x < TE)
    s_base[threadIdx.x] = atomicAdd(&cursor[threadIdx.x], s_cnt[threadIdx.x]);
  __syncthreads();
  int p0 = s_off[e0] + s_base[e0] + r0;
  int p1 = s_off[e1] + s_base[e1] + r1;
  token_perm[p0] = t; gate_perm[p0] = top_g[t * 2];
  token_perm[p1] = t; gate_perm[p1] = top_g[t * 2 + 1];
  tslot[t * 2] = p0; tslot[t * 2 + 1] = p1;
}

extern "C" void kernel_launch(void* const* d_in, const int* in_sizes, int n_in,
                              void* d_out, int out_size, void* d_ws, size_t ws_size,
                              hipStream_t stream) {
  const float* x     = (const float*)d_in[0];
  const float* n1w   = (const float*)d_in[1];
  const float* n2w   = (const float*)d_in[2];
  const float* w_qkv = (const float*)d_in[3];
  const float* b_qkv = (const float*)d_in[4];
  const float* w_o   = (const float*)d_in[5];
  const float* b_o   = (const float*)d_in[6];
  const float* rw    = (const float*)d_in[7];
  const float* rb    = (const float*)d_in[8];
  const float* w1    = (const float*)d_in[9];
  const float* b1    = (const float*)d_in[10];
  const float* w2    = (const float*)d_in[11];
  const float* b2    = (const float*)d_in[12];
  float* out = (float*)d_out;
  char* ws = (char*)d_ws;

  size_t o = 0;
  auto give = [&](size_t bytes) -> char* {
    char* p = ws + o;
    o += (bytes + 255) & ~(size_t)255;
    return p;
  };
  unsigned short* w1T = (unsigned short*)give(8ull * 4096 * 1024 * 2);   // 64MB
  unsigned short* w2T = (unsigned short*)give(8ull * 1024 * 4096 * 2);   // 64MB
  unsigned short* wo0 = (unsigned short*)give(1024ull * 1024 * 2);
  unsigned short* wo1 = (unsigned short*)give(1024ull * 1024 * 2);
  unsigned short* h2  = (unsigned short*)give((size_t)TT * TD * 2);      // 8MB
  int*   counts = (int*)give(TE * 4);
  int*   cursor = (int*)give(TE * 4);
  float* psum   = (float*)give(TE * 4);
  int*   top_e  = (int*)give(2ull * TT * 4);
  float* top_g  = (float*)give(2ull * TT * 4);
  int*   tperm  = (int*)give(2ull * TT * 4);
  float* gperm  = (float*)give(2ull * TT * 4);
  int*   tslot  = (int*)give(2ull * TT * 4);
  unsigned short* wq0 = (unsigned short*)give(3072ull * 1024 * 2);
  unsigned short* wq1 = (unsigned short*)give(3072ull * 1024 * 2);
  unsigned short* ysb = (unsigned short*)give(2ull * 2 * TT * TD * 2);   // 32MB (2 K-halves, bf16)
  // pool B: h1 pair (dead after gemm2<0>) aliased with ao pair (dead after gemm2<1>)
  char* poolB = give(2ull * TT * TD * 2);                                // 16MB
  unsigned short* h10 = (unsigned short*)poolB;
  unsigned short* h11 = (unsigned short*)(poolB + (size_t)TT * TD * 2);
  unsigned short* ao0 = h10; unsigned short* ao1 = h11;
  // pool C: qkv split pair (dead after attn) aliased with he (born at MoE up)
  char* poolC = give(64ull * 1024 * 1024);                               // 64MB
  unsigned short* qs0 = (unsigned short*)poolC;
  unsigned short* qs1 = (unsigned short*)(poolC + 3ull * PSTR * 2);
  unsigned short* he  = (unsigned short*)poolC;                          // [2TT][TF] bf16

  // weight prep (64x64 transpose tiles)
  tcvt_split_kernel<<<dim3(48, 16, 1), 256, 0, stream>>>(w_qkv, wq0, wq1, 1024, 3072);
  tcvt_split_kernel<<<dim3(16, 16, 1), 256, 0, stream>>>(w_o, wo0, wo1, 1024, 1024);
  tcvt_kernel<<<dim3(64, 16, 8), 256, 0, stream>>>(w1, w1T, 1024, 4096);
  tcvt_kernel<<<dim3(16, 64, 8), 256, 0, stream>>>(w2, w2T, 4096, 1024);

  // attention path (2-way split, 3-product; all operands pre-split)
  // rmsnorm_split block 0 also zeroes the MoE meta (counts/psum/cursor)
  rmsnorm_split_kernel<<<dim3(TT), 256, 0, stream>>>(x, n1w, h10, h11, counts, psum, cursor);
  gemm2<0><<<dim3(24, 32, 1), 256, 0, stream>>>(
      h10, h11, wq0, wq1, b_qkv, 1024, nullptr, nullptr, qs0, qs1);
  attn2_kernel<<<dim3(8, 32, 1), 512, 0, stream>>>(qs0, qs1, ao0, ao1);
  gemm2<1><<<dim3(8, 32, 1), 256, 0, stream>>>(
      ao0, ao1, wo0, wo1, b_o, 1024, out, x, nullptr, nullptr);

  // MoE path (bf16); router fuses the rmsnorm h2 write
  router_kernel<<<dim3(64), 256, 0, stream>>>(out, n2w, rw, rb, top_e, top_g, counts, psum, h2);
  fill_kernel<<<dim3(TT / 256), 256, 0, stream>>>(top_e, top_g, counts, cursor, tperm, gperm, tslot);
  gemm_bt<2><<<dim3(32, 32, 8), 256, 0, stream>>>(
      h2, w1T, b1, 4096, 1024, 1024, nullptr, he, counts, tperm, gperm);
  gemm_bt<3><<<dim3(8, 32, 16), 256, 0, stream>>>(
      he, w2T, b2, 1024, 2048, 4096, ysb, nullptr, counts, tperm, gperm);
  moe_reduce_kernel<<<dim3(TT), 256, 0, stream>>>(ysb, tslot, out, counts, psum);
}